// Round 11
// baseline (5241.294 us; speedup 1.0000x reference)
//
#include <hip/hip_runtime.h>
#include <hip/hip_bf16.h>
#include <math.h>

#define NTOK 197

typedef __attribute__((ext_vector_type(8))) short bfx8;
typedef __attribute__((ext_vector_type(4))) float fx4;

#define GLOAD16(gsrc, ldst) __builtin_amdgcn_global_load_lds( \
    (const __attribute__((address_space(1))) void*)(gsrc),    \
    (__attribute__((address_space(3))) void*)(ldst), 16, 0, 0)

__device__ __forceinline__ float gelu_f(float x) {
    return 0.5f * x * (1.0f + erff(x * 0.70710678118654752f));
}

// bijective XCD swizzle (T1, m204): contiguous chunk of blocks per XCD
__device__ __forceinline__ int xcd_swz(int orig, int nwg) {
    const int q8 = nwg >> 3, r8 = nwg & 7;
    const int xcd = orig & 7, idx8 = orig >> 3;
    return (xcd < r8 ? xcd * (q8 + 1) : r8 * (q8 + 1) + (xcd - r8) * q8) + idx8;
}

// ---------------------------------------------------------------------------
// Patch extraction + LayerNorm -> bf16. Coalesced float4 loads staged via LDS.
// ---------------------------------------------------------------------------
__global__ __launch_bounds__(256) void patch_ln_k(const float* __restrict__ x,
                                                  __hip_bfloat16* __restrict__ out,
                                                  const float* __restrict__ g,
                                                  const float* __restrict__ bt) {
    const int r = blockIdx.x;          // 0..12543
    const int t = threadIdx.x;
    const int b = r / 196, p = r % 196;
    const int ph = p / 14, pw = p % 14;

    __shared__ float px[768];
    if (t < 192) {
        int rr = t >> 2, seg = t & 3;
        int c = rr >> 4, h1 = rr & 15;
        const float* src = x + (((size_t)b * 3 + c) * 224 + (ph * 16 + h1)) * 224
                             + pw * 16 + seg * 4;
        float4 v4 = *(const float4*)src;
        px[(h1 * 16 + seg * 4 + 0) * 3 + c] = v4.x;
        px[(h1 * 16 + seg * 4 + 1) * 3 + c] = v4.y;
        px[(h1 * 16 + seg * 4 + 2) * 3 + c] = v4.z;
        px[(h1 * 16 + seg * 4 + 3) * 3 + c] = v4.w;
    }
    __syncthreads();

    float v[3];
    #pragma unroll
    for (int i = 0; i < 3; ++i) v[i] = px[t + i * 256];
    float s = v[0] + v[1] + v[2];
    float sq = v[0]*v[0] + v[1]*v[1] + v[2]*v[2];
    #pragma unroll
    for (int off = 32; off; off >>= 1) { s += __shfl_xor(s, off); sq += __shfl_xor(sq, off); }
    __shared__ float ss[4], s2[4];
    const int w = t >> 6;
    if ((t & 63) == 0) { ss[w] = s; s2[w] = sq; }
    __syncthreads();
    s  = ss[0] + ss[1] + ss[2] + ss[3];
    sq = s2[0] + s2[1] + s2[2] + s2[3];
    const float inv = 1.0f / 768.0f;
    float mu = s * inv;
    float var = sq * inv - mu * mu;
    float rstd = rsqrtf(var + 1e-5f);
    __hip_bfloat16* o = out + (size_t)r * 768;
    #pragma unroll
    for (int i = 0; i < 3; ++i) {
        int d = t + i * 256;
        o[d] = (__hip_bfloat16)((v[i] - mu) * rstd * g[d] + bt[d]);
    }
}

// ---------------------------------------------------------------------------
// Row LayerNorm over 768 fp32 -> OT
// ---------------------------------------------------------------------------
template <typename OT>
__global__ __launch_bounds__(256) void ln_k(const float* __restrict__ in,
                                            OT* __restrict__ out,
                                            const float* __restrict__ g,
                                            const float* __restrict__ bt) {
    const int r = blockIdx.x;
    const int t = threadIdx.x;
    const float* xr = in + (size_t)r * 768;
    float v0 = xr[t], v1 = xr[t + 256], v2 = xr[t + 512];
    float s = v0 + v1 + v2;
    float sq = v0*v0 + v1*v1 + v2*v2;
    #pragma unroll
    for (int off = 32; off; off >>= 1) { s += __shfl_xor(s, off); sq += __shfl_xor(sq, off); }
    __shared__ float ss[4], s2[4];
    const int w = t >> 6;
    if ((t & 63) == 0) { ss[w] = s; s2[w] = sq; }
    __syncthreads();
    s  = ss[0] + ss[1] + ss[2] + ss[3];
    sq = s2[0] + s2[1] + s2[2] + s2[3];
    const float inv = 1.0f / 768.0f;
    float mu = s * inv;
    float var = sq * inv - mu * mu;
    float rstd = rsqrtf(var + 1e-5f);
    OT* o = out + (size_t)r * 768;
    o[t]       = (OT)((v0 - mu) * rstd * g[t]       + bt[t]);
    o[t + 256] = (OT)((v1 - mu) * rstd * g[t + 256] + bt[t + 256]);
    o[t + 512] = (OT)((v2 - mu) * rstd * g[t + 512] + bt[t + 512]);
}

// ---------------------------------------------------------------------------
// LN of CLS rows only -> bf16 [128][768] (rows 64..127 zeroed)
// ---------------------------------------------------------------------------
__global__ __launch_bounds__(256) void ln_cls_k(const float* __restrict__ in,
                                                __hip_bfloat16* __restrict__ out,
                                                const float* __restrict__ g,
                                                const float* __restrict__ bt) {
    const int b = blockIdx.x;   // 0..127
    const int t = threadIdx.x;
    if (b >= 64) {
        #pragma unroll
        for (int i = 0; i < 3; ++i) out[(size_t)b * 768 + t + i * 256] = (__hip_bfloat16)0.0f;
        return;
    }
    const float* xr = in + (size_t)b * 197 * 768;
    float v0 = xr[t], v1 = xr[t + 256], v2 = xr[t + 512];
    float s = v0 + v1 + v2;
    float sq = v0*v0 + v1*v1 + v2*v2;
    #pragma unroll
    for (int off = 32; off; off >>= 1) { s += __shfl_xor(s, off); sq += __shfl_xor(sq, off); }
    __shared__ float ss[4], s2[4];
    const int w = t >> 6;
    if ((t & 63) == 0) { ss[w] = s; s2[w] = sq; }
    __syncthreads();
    s  = ss[0] + ss[1] + ss[2] + ss[3];
    sq = s2[0] + s2[1] + s2[2] + s2[3];
    const float inv = 1.0f / 768.0f;
    float mu = s * inv;
    float var = sq * inv - mu * mu;
    float rstd = rsqrtf(var + 1e-5f);
    __hip_bfloat16* o = out + (size_t)b * 768;
    o[t]       = (__hip_bfloat16)((v0 - mu) * rstd * g[t]       + bt[t]);
    o[t + 256] = (__hip_bfloat16)((v1 - mu) * rstd * g[t + 256] + bt[t + 256]);
    o[t + 512] = (__hip_bfloat16)((v2 - mu) * rstd * g[t + 512] + bt[t + 512]);
}

// ---------------------------------------------------------------------------
// z = concat(cls, p_ln) + pos  -> [64,197,768] fp32
// ---------------------------------------------------------------------------
__global__ __launch_bounds__(256) void build_z_k(const float* __restrict__ pln,
                                                 const float* __restrict__ cls,
                                                 const float* __restrict__ pos,
                                                 float* __restrict__ z) {
    size_t idx = (size_t)blockIdx.x * 256 + threadIdx.x;
    int d  = idx % 768;
    size_t tkb = idx / 768;
    int tk = tkb % 197;
    int b  = tkb / 197;
    float v = (tk == 0) ? cls[d] : pln[((size_t)b * 196 + (tk - 1)) * 768 + d];
    z[idx] = v + pos[(size_t)tk * 768 + d];
}

// ---------------------------------------------------------------------------
// Weight convert + transpose: fp32 [K,N] -> bf16 [N,K], z-strided output
// ---------------------------------------------------------------------------
__global__ __launch_bounds__(256) void wconv_k(const float* __restrict__ W,
                                               __hip_bfloat16* __restrict__ Wt,
                                               int K, int N, size_t ostride) {
    __shared__ float tl[64][65];
    const int t = threadIdx.x;
    const int n0 = blockIdx.x * 64, k0 = blockIdx.y * 64;
    const size_t ibase = (size_t)blockIdx.z * K * N;
    const size_t obase = (size_t)blockIdx.z * ostride;
    #pragma unroll
    for (int i = 0; i < 16; ++i) {
        int idx = i * 256 + t;
        int kl = idx >> 6, nl = idx & 63;
        tl[kl][nl] = W[ibase + (size_t)(k0 + kl) * N + n0 + nl];
    }
    __syncthreads();
    #pragma unroll
    for (int i = 0; i < 16; ++i) {
        int idx = i * 256 + t;
        int nl = idx >> 6, kl = idx & 63;
        Wt[obase + (size_t)(n0 + nl) * K + k0 + kl] = (__hip_bfloat16)tl[kl][nl];
    }
}

// ---------------------------------------------------------------------------
// W_head transpose: fp32 [768][1000] -> bf16 [1024][768], pad rows zeroed
// ---------------------------------------------------------------------------
__global__ __launch_bounds__(256) void whT_k(const float* __restrict__ W,
                                             __hip_bfloat16* __restrict__ Wt) {
    __shared__ float tl[64][65];
    const int t = threadIdx.x;
    const int n0 = blockIdx.x * 64, k0 = blockIdx.y * 64;
    #pragma unroll
    for (int i = 0; i < 16; ++i) {
        int idx = i * 256 + t;
        int kl = idx >> 6, nl = idx & 63;
        int n = n0 + nl;
        tl[kl][nl] = (n < 1000) ? W[(size_t)(k0 + kl) * 1000 + n] : 0.f;
    }
    __syncthreads();
    #pragma unroll
    for (int i = 0; i < 16; ++i) {
        int idx = i * 256 + t;
        int nl = idx >> 6, kl = idx & 63;
        Wt[(size_t)(n0 + nl) * 768 + k0 + kl] = (__hip_bfloat16)tl[kl][nl];
    }
}

// ---------------------------------------------------------------------------
// 128x128 bf16 MFMA GEMM, BK=64 (round-5 known-good) + XCD swizzle.
// Used for N=768 GEMMs and the head GEMM.
// ---------------------------------------------------------------------------
template <int EPI, typename OT>
__global__ __launch_bounds__(256) void mgemm_k(const __hip_bfloat16* __restrict__ A,
                                               const __hip_bfloat16* __restrict__ Wt,
                                               const float* __restrict__ bias,
                                               const float* __restrict__ resid,
                                               OT* __restrict__ C,
                                               int M, int N, int K) {
    __shared__ __align__(16) char sA[16384];
    __shared__ __align__(16) char sB[16384];
    const int t = threadIdx.x;
    const int lane = t & 63, w = t >> 6;
    const int wr = w >> 1, wc = w & 1;
    const int lrow = lane & 15, lgr = lane >> 4;

    const int gx = gridDim.x;
    const int swz = xcd_swz(blockIdx.y * gx + blockIdx.x, gx * gridDim.y);
    const int bm = (swz / gx) * 128, bn = (swz % gx) * 128;

    const __hip_bfloat16* aSrc[4];
    const __hip_bfloat16* bSrc[4];
    #pragma unroll
    for (int i = 0; i < 4; ++i) {
        int q = t + i * 256;          // 0..1023
        int r = q >> 3, c = q & 7;
        int gc = c ^ (r & 7);
        aSrc[i] = A  + (size_t)(bm + r) * K + gc * 8;
        bSrc[i] = Wt + (size_t)(bn + r) * K + gc * 8;
    }

    int aoff[4][2], boff[4][2];
    #pragma unroll
    for (int m = 0; m < 4; ++m) {
        int ra = wr * 64 + m * 16 + lrow;
        int rb = wc * 64 + m * 16 + lrow;
        #pragma unroll
        for (int ks = 0; ks < 2; ++ks) {
            aoff[m][ks] = ra * 128 + (((ks * 4 + lgr) ^ (ra & 7)) << 4);
            boff[m][ks] = rb * 128 + (((ks * 4 + lgr) ^ (rb & 7)) << 4);
        }
    }

    fx4 acc[4][4];
    #pragma unroll
    for (int m = 0; m < 4; ++m)
        #pragma unroll
        for (int n = 0; n < 4; ++n)
            #pragma unroll
            for (int e = 0; e < 4; ++e) acc[m][n][e] = 0.f;

    for (int k0 = 0; k0 < K; k0 += 64) {
        #pragma unroll
        for (int i = 0; i < 4; ++i) GLOAD16(aSrc[i] + k0, sA + (t + i * 256) * 16);
        #pragma unroll
        for (int i = 0; i < 4; ++i) GLOAD16(bSrc[i] + k0, sB + (t + i * 256) * 16);
        __syncthreads();
        #pragma unroll
        for (int ks = 0; ks < 2; ++ks) {
            bfx8 av[4], bv[4];
            #pragma unroll
            for (int m = 0; m < 4; ++m) {
                av[m] = *(const bfx8*)(sA + aoff[m][ks]);
                bv[m] = *(const bfx8*)(sB + boff[m][ks]);
            }
            #pragma unroll
            for (int m = 0; m < 4; ++m)
                #pragma unroll
                for (int n = 0; n < 4; ++n)
                    acc[m][n] = __builtin_amdgcn_mfma_f32_16x16x32_bf16(av[m], bv[n], acc[m][n], 0, 0, 0);
        }
        __syncthreads();
    }

    #pragma unroll
    for (int m = 0; m < 4; ++m) {
        #pragma unroll
        for (int n = 0; n < 4; ++n) {
            const int col = bn + wc * 64 + n * 16 + lrow;
            float bv2 = (EPI >= 1) ? bias[col] : 0.f;
            #pragma unroll
            for (int e = 0; e < 4; ++e) {
                const int row = bm + wr * 64 + m * 16 + lgr * 4 + e;
                if (row < M) {
                    float v = acc[m][n][e] + bv2;
                    if (EPI == 2) v = gelu_f(v);
                    if (EPI == 3) v += resid[(size_t)row * N + col];
                    C[(size_t)row * N + col] = (OT)v;
                }
            }
        }
    }
}

// ---------------------------------------------------------------------------
// 256x256 bf16 MFMA GEMM, 4-phase quadrant schedule + counted vmcnt (m201
// geometry). 512 thr / 8 waves (2M x 4N), wave output 128x64, acc 8x4.
// LDS 128 KiB: A/B each 2 slots x 2 halves x 16 KiB. 1 block/CU.
// Per K-tile j (slot s=j&1), phases = C-quadrants:
//   p0: read A(m0-3,ks0/1)+B(n0-1); stage Ah0(j+1)->s^1; bar; lgkm0; 16 MFMA; bar
//   p1: read B(n2-3);               stage Ah1(j+1)->s^1; bar; lgkm0; 16 MFMA; bar
//   p2: read A(m4-7);               stage Bh0(j+2)->s;   bar; lgkm0; 16 MFMA; bar
//   p3: (no reads)                  stage Bh1(j+2)->s;   bar;        16 MFMA;
//       vmcnt(4 | 0 at tail); bar
// Hazards: Ah(j+1)->s^1 safe (tile j-1 A reads done at its p2); Bh(j+2)->s
// safe (tile j B reads done at p1). vmcnt(4) leaves only Bh(j+2)'s 4 loads
// outstanding; A(j+1)/B(j+1) retired in-order => tile j+1 resident.
// N%256==0, K%64==0, NK>=2. A needs ceil(M/256)*256 readable rows.
// ---------------------------------------------------------------------------
template <int EPI, typename OT>
__global__ __launch_bounds__(512, 1) void mgemm256sq_k(const __hip_bfloat16* __restrict__ A,
                                                       const __hip_bfloat16* __restrict__ Wt,
                                                       const float* __restrict__ bias,
                                                       const float* __restrict__ resid,
                                                       OT* __restrict__ C,
                                                       int M, int N, int K) {
    __shared__ __align__(16) char sA[4 * 16384];   // [slot][half]
    __shared__ __align__(16) char sB[4 * 16384];
    const int t = threadIdx.x;            // 0..511
    const int lane = t & 63, w = t >> 6;
    const int wr = w >> 2, wc = w & 3;    // 2M x 4N -> wave 128 x 64
    const int lrow = lane & 15, lgr = lane >> 4;

    const int gx = gridDim.x;
    const int swz = xcd_swz(blockIdx.y * gx + blockIdx.x, gx * gridDim.y);
    const int bm = (swz / gx) * 256, bn = (swz % gx) * 256;

    const int r0 = t >> 3, c0 = t & 7, gc0 = c0 ^ (r0 & 7);
    const int r1 = (t + 512) >> 3,     gc1 = c0 ^ (r1 & 7);
    const __hip_bfloat16* aS0 = A  + (size_t)(bm + r0) * K + gc0 * 8;
    const __hip_bfloat16* aS1 = A  + (size_t)(bm + r1) * K + gc1 * 8;
    const __hip_bfloat16* bS0 = Wt + (size_t)(bn + r0) * K + gc0 * 8;
    const __hip_bfloat16* bS1 = Wt + (size_t)(bn + r1) * K + gc1 * 8;
    const size_t hstep = (size_t)128 * K;

#define STAGE_A(h, sl, jj) do { \
    GLOAD16(aS0 + (size_t)(h) * hstep + (jj) * 64, sA + ((sl) * 2 + (h)) * 16384 + t * 16); \
    GLOAD16(aS1 + (size_t)(h) * hstep + (jj) * 64, sA + ((sl) * 2 + (h)) * 16384 + (t + 512) * 16); \
} while (0)
#define STAGE_B(h, sl, jj) do { \
    GLOAD16(bS0 + (size_t)(h) * hstep + (jj) * 64, sB + ((sl) * 2 + (h)) * 16384 + t * 16); \
    GLOAD16(bS1 + (size_t)(h) * hstep + (jj) * 64, sB + ((sl) * 2 + (h)) * 16384 + (t + 512) * 16); \
} while (0)

    // fragment offsets local to a 128x64 half-buffer
    int aoff[8][2], boff[4][2];
    #pragma unroll
    for (int m = 0; m < 8; ++m) {
        int lr = m * 16 + lrow;
        #pragma unroll
        for (int ks = 0; ks < 2; ++ks)
            aoff[m][ks] = lr * 128 + (((ks * 4 + lgr) ^ (lr & 7)) << 4);
    }
    #pragma unroll
    for (int n = 0; n < 4; ++n) {
        int lb = (wc & 1) * 64 + n * 16 + lrow;
        #pragma unroll
        for (int ks = 0; ks < 2; ++ks)
            boff[n][ks] = lb * 128 + (((ks * 4 + lgr) ^ (lb & 7)) << 4);
    }

    fx4 acc[8][4];
    #pragma unroll
    for (int m = 0; m < 8; ++m)
        #pragma unroll
        for (int n = 0; n < 4; ++n)
            #pragma unroll
            for (int e = 0; e < 4; ++e) acc[m][n][e] = 0.f;

    const int NK = K >> 6;

    // ---- prologue: tile0 (slot0, 4 halves) + tile1 B halves (slot1) ----
    STAGE_A(0, 0, 0); STAGE_A(1, 0, 0);
    STAGE_B(0, 0, 0); STAGE_B(1, 0, 0);
    STAGE_B(0, 1, 1); STAGE_B(1, 1, 1);
    asm volatile("s_waitcnt vmcnt(4)" ::: "memory");   // tile0's 8 loads done
    __builtin_amdgcn_sched_barrier(0);
    __builtin_amdgcn_s_barrier();

    for (int j = 0; j < NK; ++j) {
        const int s = j & 1;
        const char* myA = sA + (s * 2 + wr) * 16384;
        const char* myB = sB + (s * 2 + (wc >> 1)) * 16384;
        bfx8 av[8], bl[4], bh[4];

        // ---- p0: quadrant (m0-3, n0-1) ----
        #pragma unroll
        for (int m = 0; m < 4; ++m) {
            av[m * 2]     = *(const bfx8*)(myA + aoff[m][0]);
            av[m * 2 + 1] = *(const bfx8*)(myA + aoff[m][1]);
        }
        #pragma unroll
        for (int n = 0; n < 2; ++n) {
            bl[n * 2]     = *(const bfx8*)(myB + boff[n][0]);
            bl[n * 2 + 1] = *(const bfx8*)(myB + boff[n][1]);
        }
        if (j + 1 < NK) STAGE_A(0, s ^ 1, j + 1);
        __builtin_amdgcn_s_barrier();
        asm volatile("s_waitcnt lgkmcnt(0)" ::: "memory");
        __builtin_amdgcn_sched_barrier(0);
        __builtin_amdgcn_s_setprio(1);
        #pragma unroll
        for (int m = 0; m < 4; ++m)
            #pragma unroll
            for (int n = 0; n < 2; ++n) {
                acc[m][n] = __builtin_amdgcn_mfma_f32_16x16x32_bf16(av[m*2],   bl[n*2],   acc[m][n], 0, 0, 0);
                acc[m][n] = __builtin_amdgcn_mfma_f32_16x16x32_bf16(av[m*2+1], bl[n*2+1], acc[m][n], 0, 0, 0);
            }
        __builtin_amdgcn_s_setprio(0);
        __builtin_amdgcn_s_barrier();

        // ---- p1: quadrant (m0-3, n2-3) ----
        #pragma unroll
        for (int n = 0; n < 2; ++n) {
            bh[n * 2]     = *(const bfx8*)(myB + boff[2 + n][0]);
            bh[n * 2 + 1] = *(const bfx8*)(myB + boff[2 + n][1]);
        }
        if (j + 1 < NK) STAGE_A(1, s ^ 1, j + 1);
        __builtin_amdgcn_s_barrier();
        asm volatile("s_waitcnt lgkmcnt(0)" ::: "memory");
        __builtin_amdgcn_sched_barrier(0);
        __builtin_amdgcn_s_setprio(1);
        #pragma unroll
        for (int m = 0; m < 4; ++m)
            #pragma unroll
            for (int n = 0; n < 2; ++n) {
                acc[m][2+n] = __builtin_amdgcn_mfma_f32_16x16x32_bf16(av[m*2],   bh[n*2],   acc[m][2+n], 0, 0, 0);
                acc[m][2+n] = __builtin_amdgcn_mfma_f32_16x16x32_bf16(av[m*2+1], bh[n*2+1], acc[m][2+n], 0, 0, 0);
            }
        __builtin_amdgcn_s_setprio(0);
        __builtin_amdgcn_s_barrier();

        // ---- p2: quadrant (m4-7, n0-1) ----
        #pragma unroll
        for (int m = 0; m < 4; ++m) {
            av[m * 2]     = *(const bfx8*)(myA + aoff[4 + m][0]);
            av[m * 2 + 1] = *(const bfx8*)(myA + aoff[4 + m][1]);
        }
        if (j + 2 < NK) STAGE_B(0, s, j + 2);
        __builtin_amdgcn_s_barrier();
        asm volatile("s_waitcnt lgkmcnt(0)" ::: "memory");
        __builtin_amdgcn_sched_barrier(0);
        __builtin_amdgcn_s_setprio(1);
        #pragma unroll
        for (int m = 0; m < 4; ++m)
            #pragma unroll
            for (int n = 0; n < 2; ++n) {
                acc[4+m][n] = __builtin_amdgcn_mfma_f32_16x16x32_bf16(av[m*2],   bl[n*2],   acc[4+m][n], 0, 0, 0);
                acc[4+m][n] = __builtin_amdgcn_mfma_f32_16x16x32_bf16(av[m*2+1], bl[n*2+1], acc[4+m][n], 0, 0, 0);
            }
        __builtin_amdgcn_s_setprio(0);
        __builtin_amdgcn_s_barrier();

        // ---- p3: quadrant (m4-7, n2-3) ----
        if (j + 2 < NK) STAGE_B(1, s, j + 2);
        __builtin_amdgcn_s_barrier();
        __builtin_amdgcn_s_setprio(1);
        #pragma unroll
        for (int m = 0; m < 4; ++m)
            #pragma unroll
            for (int n = 0; n < 2; ++n) {
                acc[4+m][2+n] = __builtin_amdgcn_mfma_f32_16x16x32_bf16(av[m*2],   bh[n*2],   acc[4+m][2+n], 0, 0, 0);
                acc[4+m][2+n] = __builtin_amdgcn_mfma_f32_16x16x32_bf16(av[m*2+1], bh[n*2+1], acc[4+m][2+n], 0, 0, 0);
            }
        __builtin_amdgcn_s_setprio(0);
        if (j + 1 < NK) {
            if (j + 2 < NK) asm volatile("s_waitcnt vmcnt(4)" ::: "memory");
            else            asm volatile("s_waitcnt vmcnt(0)" ::: "memory");
            __builtin_amdgcn_sched_barrier(0);
            __builtin_amdgcn_s_barrier();
        }
    }
    asm volatile("s_waitcnt vmcnt(0)" ::: "memory");
#undef STAGE_A
#undef STAGE_B

    // ---- epilogue ----
    #pragma unroll
    for (int m = 0; m < 8; ++m) {
        #pragma unroll
        for (int n = 0; n < 4; ++n) {
            const int col = bn + wc * 64 + n * 16 + lrow;
            float bv2 = (EPI >= 1) ? bias[col] : 0.f;
            #pragma unroll
            for (int e = 0; e < 4; ++e) {
                const int row = bm + wr * 128 + m * 16 + lgr * 4 + e;
                if (row < M) {
                    float v = acc[m][n][e] + bv2;
                    if (EPI == 2) v = gelu_f(v);
                    if (EPI == 3) v += resid[(size_t)row * N + col];
                    C[(size_t)row * N + col] = (OT)v;
                }
            }
        }
    }
}

// ---------------------------------------------------------------------------
// MFMA fused attention on fused QKV buffer (row stride 2304).
// ---------------------------------------------------------------------------
__global__ __launch_bounds__(256) void attn_k(const __hip_bfloat16* __restrict__ QKV,
                                              __hip_bfloat16* __restrict__ O) {
    __shared__ __align__(16) char Ks[224 * 128];   // 28672
    __shared__ __align__(16) char VTs[64 * 464];   // 29696
    __shared__ __align__(16) char Ps[4][7424];     // 4 x (16 rows x 464B)

    const int h = blockIdx.x;
    const int b = blockIdx.y;
    const int t = threadIdx.x;
    const int lane = t & 63, w = t >> 6;
    const int rho = lane & 15, g = lane >> 4;
    const size_t base = (size_t)b * NTOK * 2304;
    const int qoff = h * 64, koff = 768 + h * 64, voff = 1536 + h * 64;
    const size_t obase = ((size_t)b * NTOK) * 768 + h * 64;

    #pragma unroll
    for (int i = 0; i < 7; ++i) {
        int q = t + i * 256;            // 0..1791
        int j = q >> 3, c = q & 7;
        int gc = c ^ (j & 7);
        GLOAD16(QKV + base + (size_t)j * 2304 + koff + gc * 8, Ks + q * 16);
    }
    #pragma unroll
    for (int i = 0; i < 7; ++i) {
        int q = t + i * 256;
        int tok = q >> 3, c = q & 7;
        bfx8 vv = {0, 0, 0, 0, 0, 0, 0, 0};
        if (tok < NTOK) vv = *(const bfx8*)(QKV + base + (size_t)tok * 2304 + voff + c * 8);
        #pragma unroll
        for (int u = 0; u < 8; ++u)
            *(unsigned short*)(VTs + (c * 8 + u) * 464 + tok * 2) = (unsigned short)vv[u];
    }
    __syncthreads();

    char* Pw = Ps[w];

    for (int qt = w; qt < 13; qt += 4) {
        const int q0 = qt * 16;
        fx4 s[13];
        #pragma unroll
        for (int nt = 0; nt < 13; ++nt)
            #pragma unroll
            for (int e = 0; e < 4; ++e) s[nt][e] = 0.f;
        #pragma unroll
        for (int ks = 0; ks < 2; ++ks) {
            bfx8 av = *(const bfx8*)(QKV + base + (size_t)(q0 + rho) * 2304 + qoff + ks * 32 + g * 8);
            #pragma unroll
            for (int nt = 0; nt < 13; ++nt) {
                int r = nt * 16 + rho;
                bfx8 bv = *(const bfx8*)(Ks + r * 128 + (((ks * 4 + g) ^ (r & 7)) << 4));
                s[nt] = __builtin_amdgcn_mfma_f32_16x16x32_bf16(av, bv, s[nt], 0, 0, 0);
            }
        }
        float mx[4] = {-1e30f, -1e30f, -1e30f, -1e30f};
        #pragma unroll
        for (int nt = 0; nt < 13; ++nt) {
            #pragma unroll
            for (int e = 0; e < 4; ++e) {
                float v = s[nt][e] * 0.125f;
                if (nt == 12 && rho >= 5) v = -1e30f;
                s[nt][e] = v;
                mx[e] = fmaxf(mx[e], v);
            }
        }
        #pragma unroll
        for (int off = 1; off < 16; off <<= 1)
            #pragma unroll
            for (int e = 0; e < 4; ++e) mx[e] = fmaxf(mx[e], __shfl_xor(mx[e], off));
        float sm[4] = {0.f, 0.f, 0.f, 0.f};
        #pragma unroll
        for (int nt = 0; nt < 13; ++nt)
            #pragma unroll
            for (int e = 0; e < 4; ++e) {
                float p = __expf(s[nt][e] - mx[e]);
                s[nt][e] = p;
                sm[e] += p;
            }
        #pragma unroll
        for (int off = 1; off < 16; off <<= 1)
            #pragma unroll
            for (int e = 0; e < 4; ++e) sm[e] += __shfl_xor(sm[e], off);
        float inv[4];
        #pragma unroll
        for (int e = 0; e < 4; ++e) inv[e] = 1.0f / sm[e];

        #pragma unroll
        for (int nt = 0; nt < 13; ++nt)
            #pragma unroll
            for (int e = 0; e < 4; ++e) {
                int row = g * 4 + e;
                int col = nt * 16 + rho;
                *(__hip_bfloat16*)(Pw + row * 464 + col * 2) =
                    (__hip_bfloat16)(s[nt][e] * inv[e]);
            }
        #pragma unroll
        for (int e = 0; e < 4; ++e)
            *(__hip_bfloat16*)(Pw + (g * 4 + e) * 464 + (208 + rho) * 2) = (__hip_bfloat16)0.0f;

        __builtin_amdgcn_sched_barrier(0);
        asm volatile("s_waitcnt lgkmcnt(0)" ::: "memory");
        __builtin_amdgcn_sched_barrier(0);

        #pragma unroll
        for (int dt = 0; dt < 4; ++dt) {
            fx4 o;
            #pragma unroll
            for (int e = 0; e < 4; ++e) o[e] = 0.f;
            #pragma unroll
            for (int ks = 0; ks < 7; ++ks) {
                bfx8 pa = *(const bfx8*)(Pw + rho * 464 + (ks * 4 + g) * 16);
                bfx8 bv = *(const bfx8*)(VTs + (dt * 16 + rho) * 464 + (ks * 4 + g) * 16);
                o = __builtin_amdgcn_mfma_f32_16x16x32_bf16(pa, bv, o, 0, 0, 0);
            }
            #pragma unroll
            for (int e = 0; e < 4; ++e) {
                int qrow = q0 + g * 4 + e;
                if (qrow < NTOK)
                    O[obase + (size_t)qrow * 768 + dt * 16 + rho] = (__hip_bfloat16)o[e];
            }
        }
    }
}

// ---------------------------------------------------------------------------
// Head softmax: out[b,:] = softmax(logits[b,:1000] + b_head)
// ---------------------------------------------------------------------------
__global__ __launch_bounds__(256) void shead_k(const float* __restrict__ logits,
                                               const float* __restrict__ bh,
                                               float* __restrict__ out) {
    const int b = blockIdx.x;
    const int t = threadIdx.x;
    __shared__ float lg[1000];
    __shared__ float red[4];

    for (int c = t; c < 1000; c += 256) lg[c] = logits[(size_t)b * 1024 + c] + bh[c];
    __syncthreads();

    float m = -1e30f;
    for (int c = t; c < 1000; c += 256) m = fmaxf(m, lg[c]);
    #pragma unroll
    for (int off = 32; off; off >>= 1) m = fmaxf(m, __shfl_xor(m, off));
    if ((t & 63) == 0) red[t >> 6] = m;
    __syncthreads();
    m = fmaxf(fmaxf(red[0], red[1]), fmaxf(red[2], red[3]));
    __syncthreads();

    float sum = 0.f;
    for (int c = t; c < 1000; c += 256) sum += __expf(lg[c] - m);
    #pragma unroll
    for (int off = 32; off; off >>= 1) sum += __shfl_xor(sum, off);
    if ((t & 63) == 0) red[t >> 6] = sum;
    __syncthreads();
    sum = red[0] + red[1] + red[2] + red[3];
    const float invs = 1.0f / sum;
    for (int c = t; c < 1000; c += 256) out[(size_t)b * 1000 + c] = __expf(lg[c] - m) * invs;
}

// ---------------------------------------------------------------------------
// Driver
// ---------------------------------------------------------------------------
extern "C" void kernel_launch(void* const* d_in, const int* in_sizes, int n_in,
                              void* d_out, int out_size, void* d_ws, size_t ws_size,
                              hipStream_t stream) {
    const float* x        = (const float*)d_in[0];
    const float* ln_p_g   = (const float*)d_in[1];
    const float* ln_p_b   = (const float*)d_in[2];
    const float* W_patch  = (const float*)d_in[3];
    const float* b_patch  = (const float*)d_in[4];
    const float* ln_e_g   = (const float*)d_in[5];
    const float* ln_e_b   = (const float*)d_in[6];
    const float* pos_emb  = (const float*)d_in[7];
    const float* cls_tok  = (const float*)d_in[8];
    const float* ln_a_g   = (const float*)d_in[9];
    const float* ln_a_b   = (const float*)d_in[10];
    const float* Wq       = (const float*)d_in[11];
    const float* Wk       = (const float*)d_in[12];
    const float* Wv       = (const float*)d_in[13];
    const float* Wo       = (const float*)d_in[14];
    const float* bo       = (const float*)d_in[15];
    const float* ln_f_g   = (const float*)d_in[16];
    const float* ln_f_b   = (const float*)d_in[17];
    const float* W1       = (const float*)d_in[18];
    const float* b1       = (const float*)d_in[19];
    const float* W2       = (const float*)d_in[20];
    const float* b2       = (const float*)d_in[21];
    const float* ln_out_g = (const float*)d_in[22];
    const float* ln_out_b = (const float*)d_in[23];
    const float* W_head   = (const float*)d_in[24];
    const float* b_head   = (const float*)d_in[25];

    typedef __hip_bfloat16 bf;
    const int M  = 12608;               // 64*197
    const int MP = 12800;               // padded to 50*256
    char* p = (char*)d_ws;

    float* Z   = (float*)p;            p += (size_t)MP * 768 * 4;      // fp32 residual
    bf* XA     = (bf*)p;               p += (size_t)MP * 768 * 2;      // LN out (bf16)
    bf* QKV    = (bf*)p;               p += (size_t)MP * 2304 * 2;     // fused q,k,v
    bf* OB     = (bf*)p;               p += (size_t)MP * 768 * 2;
    char* FFHc = p;                    p += (size_t)MP * 3072 * 2;     // bf16 GELU buf
    bf* FFH    = (bf*)FFHc;
    float* PE  = (float*)FFHc;                                          // alias: patch-embed fp32
    float* E2  = (float*)(FFHc + (size_t)MP * 768 * 4);                 // alias: ln_e out fp32
    bf* WQKVT  = (bf*)p;               p += (size_t)12 * 2304 * 768 * 2;
    bf* WoT    = (bf*)p;               p += (size_t)12 * 768 * 768 * 2;
    bf* W1T    = (bf*)p;               p += (size_t)12 * 3072 * 768 * 2;
    bf* W2T    = (bf*)p;               p += (size_t)12 * 768 * 3072 * 2;
    bf* WpT    = (bf*)p;               p += (size_t)768 * 768 * 2;
    bf* WhT    = (bf*)p;               p += (size_t)1024 * 768 * 2;
    bf* CLS    = (bf*)p;               p += (size_t)128 * 768 * 2;
    float* LOG = (float*)p;            p += (size_t)64 * 1024 * 4;

    const size_t QKVS = (size_t)2304 * 768;

    // weight convert + transpose (every launch)
    wconv_k<<<dim3(12, 12, 12), 256, 0, stream>>>(Wq, WQKVT,             768, 768,  QKVS);
    wconv_k<<<dim3(12, 12, 12), 256, 0, stream>>>(Wk, WQKVT + 768 * 768, 768, 768,  QKVS);
    wconv_k<<<dim3(12, 12, 12), 256, 0, stream>>>(Wv, WQKVT + 1536 * 768,768, 768,  QKVS);
    wconv_k<<<dim3(12, 12, 12), 256, 0, stream>>>(Wo, WoT,  768, 768,  (size_t)768 * 768);
    wconv_k<<<dim3(48, 12, 12), 256, 0, stream>>>(W1, W1T,  768, 3072, (size_t)3072 * 768);
    wconv_k<<<dim3(12, 48, 12), 256, 0, stream>>>(W2, W2T,  3072, 768, (size_t)768 * 3072);
    wconv_k<<<dim3(12, 12, 1),  256, 0, stream>>>(W_patch, WpT, 768, 768, 0);
    whT_k  <<<dim3(16, 12),     256, 0, stream>>>(W_head, WhT);

    // patch embed pipeline
    patch_ln_k<<<12544, 256, 0, stream>>>(x, XA, ln_p_g, ln_p_b);
    mgemm_k<1, float><<<dim3(6, 98), 256, 0, stream>>>(XA, WpT, b_patch, nullptr, PE, 12544, 768, 768);
    ln_k<float><<<12544, 256, 0, stream>>>(PE, E2, ln_e_g, ln_e_b);
    build_z_k<<<37824, 256, 0, stream>>>(E2, cls_tok, pos_emb, Z);

    for (int i = 0; i < 12; ++i) {
        bf* WQKVT_i = WQKVT + (size_t)i * QKVS;
        bf* WoT_i   = WoT + (size_t)i * 768 * 768;
        bf* W1T_i   = W1T + (size_t)i * 3072 * 768;
        bf* W2T_i   = W2T + (size_t)i * 768 * 3072;

        ln_k<bf><<<M, 256, 0, stream>>>(Z, XA, ln_a_g + (size_t)i * 768, ln_a_b + (size_t)i * 768);
        mgemm256sq_k<0, bf><<<dim3(9, 50), 512, 0, stream>>>(XA, WQKVT_i, nullptr, nullptr, QKV, M, 2304, 768);
        attn_k<<<dim3(12, 64), 256, 0, stream>>>(QKV, OB);
        mgemm_k<3, float><<<dim3(6, 99), 256, 0, stream>>>(OB, WoT_i, bo + (size_t)i * 768, Z, Z, M, 768, 768);
        ln_k<bf><<<M, 256, 0, stream>>>(Z, XA, ln_f_g + (size_t)i * 768, ln_f_b + (size_t)i * 768);
        mgemm256sq_k<2, bf><<<dim3(12, 50), 512, 0, stream>>>(XA, W1T_i, b1 + (size_t)i * 3072, nullptr, FFH, M, 3072, 768);
        mgemm_k<3, float><<<dim3(6, 99), 256, 0, stream>>>(FFH, W2T_i, b2 + (size_t)i * 768, Z, Z, M, 768, 3072);
    }

    // head: LN(CLS rows) -> logits GEMM (128^2 kernel) -> softmax
    ln_cls_k<<<128, 256, 0, stream>>>(Z, CLS, ln_out_g, ln_out_b);
    mgemm_k<0, float><<<dim3(8, 1), 256, 0, stream>>>(CLS, WhT, nullptr, nullptr, LOG, 64, 1024, 768);
    shead_k<<<64, 256, 0, stream>>>(LOG, b_head, (float*)d_out);
}

// Round 12
// 4964.293 us; speedup vs baseline: 1.0558x; 1.0558x over previous
//
#include <hip/hip_runtime.h>
#include <hip/hip_bf16.h>
#include <math.h>

#define NTOK 197

typedef __attribute__((ext_vector_type(8))) short bfx8;
typedef __attribute__((ext_vector_type(4))) float fx4;

#define GLOAD16(gsrc, ldst) __builtin_amdgcn_global_load_lds( \
    (const __attribute__((address_space(1))) void*)(gsrc),    \
    (__attribute__((address_space(3))) void*)(ldst), 16, 0, 0)

__device__ __forceinline__ float gelu_f(float x) {
    return 0.5f * x * (1.0f + erff(x * 0.70710678118654752f));
}

// bijective XCD swizzle (T1, m204): contiguous chunk of blocks per XCD
__device__ __forceinline__ int xcd_swz(int orig, int nwg) {
    const int q8 = nwg >> 3, r8 = nwg & 7;
    const int xcd = orig & 7, idx8 = orig >> 3;
    return (xcd < r8 ? xcd * (q8 + 1) : r8 * (q8 + 1) + (xcd - r8) * q8) + idx8;
}

// ---------------------------------------------------------------------------
// Patch extraction + LayerNorm -> bf16. Coalesced float4 loads staged via LDS.
// ---------------------------------------------------------------------------
__global__ __launch_bounds__(256) void patch_ln_k(const float* __restrict__ x,
                                                  __hip_bfloat16* __restrict__ out,
                                                  const float* __restrict__ g,
                                                  const float* __restrict__ bt) {
    const int r = blockIdx.x;          // 0..12543
    const int t = threadIdx.x;
    const int b = r / 196, p = r % 196;
    const int ph = p / 14, pw = p % 14;

    __shared__ float px[768];
    if (t < 192) {
        int rr = t >> 2, seg = t & 3;
        int c = rr >> 4, h1 = rr & 15;
        const float* src = x + (((size_t)b * 3 + c) * 224 + (ph * 16 + h1)) * 224
                             + pw * 16 + seg * 4;
        float4 v4 = *(const float4*)src;
        px[(h1 * 16 + seg * 4 + 0) * 3 + c] = v4.x;
        px[(h1 * 16 + seg * 4 + 1) * 3 + c] = v4.y;
        px[(h1 * 16 + seg * 4 + 2) * 3 + c] = v4.z;
        px[(h1 * 16 + seg * 4 + 3) * 3 + c] = v4.w;
    }
    __syncthreads();

    float v[3];
    #pragma unroll
    for (int i = 0; i < 3; ++i) v[i] = px[t + i * 256];
    float s = v[0] + v[1] + v[2];
    float sq = v[0]*v[0] + v[1]*v[1] + v[2]*v[2];
    #pragma unroll
    for (int off = 32; off; off >>= 1) { s += __shfl_xor(s, off); sq += __shfl_xor(sq, off); }
    __shared__ float ss[4], s2[4];
    const int w = t >> 6;
    if ((t & 63) == 0) { ss[w] = s; s2[w] = sq; }
    __syncthreads();
    s  = ss[0] + ss[1] + ss[2] + ss[3];
    sq = s2[0] + s2[1] + s2[2] + s2[3];
    const float inv = 1.0f / 768.0f;
    float mu = s * inv;
    float var = sq * inv - mu * mu;
    float rstd = rsqrtf(var + 1e-5f);
    __hip_bfloat16* o = out + (size_t)r * 768;
    #pragma unroll
    for (int i = 0; i < 3; ++i) {
        int d = t + i * 256;
        o[d] = (__hip_bfloat16)((v[i] - mu) * rstd * g[d] + bt[d]);
    }
}

// ---------------------------------------------------------------------------
// Row LayerNorm over 768 fp32 -> OT
// ---------------------------------------------------------------------------
template <typename OT>
__global__ __launch_bounds__(256) void ln_k(const float* __restrict__ in,
                                            OT* __restrict__ out,
                                            const float* __restrict__ g,
                                            const float* __restrict__ bt) {
    const int r = blockIdx.x;
    const int t = threadIdx.x;
    const float* xr = in + (size_t)r * 768;
    float v0 = xr[t], v1 = xr[t + 256], v2 = xr[t + 512];
    float s = v0 + v1 + v2;
    float sq = v0*v0 + v1*v1 + v2*v2;
    #pragma unroll
    for (int off = 32; off; off >>= 1) { s += __shfl_xor(s, off); sq += __shfl_xor(sq, off); }
    __shared__ float ss[4], s2[4];
    const int w = t >> 6;
    if ((t & 63) == 0) { ss[w] = s; s2[w] = sq; }
    __syncthreads();
    s  = ss[0] + ss[1] + ss[2] + ss[3];
    sq = s2[0] + s2[1] + s2[2] + s2[3];
    const float inv = 1.0f / 768.0f;
    float mu = s * inv;
    float var = sq * inv - mu * mu;
    float rstd = rsqrtf(var + 1e-5f);
    OT* o = out + (size_t)r * 768;
    o[t]       = (OT)((v0 - mu) * rstd * g[t]       + bt[t]);
    o[t + 256] = (OT)((v1 - mu) * rstd * g[t + 256] + bt[t + 256]);
    o[t + 512] = (OT)((v2 - mu) * rstd * g[t + 512] + bt[t + 512]);
}

// ---------------------------------------------------------------------------
// LN of CLS rows only -> bf16 [128][768] (rows 64..127 zeroed)
// ---------------------------------------------------------------------------
__global__ __launch_bounds__(256) void ln_cls_k(const float* __restrict__ in,
                                                __hip_bfloat16* __restrict__ out,
                                                const float* __restrict__ g,
                                                const float* __restrict__ bt) {
    const int b = blockIdx.x;   // 0..127
    const int t = threadIdx.x;
    if (b >= 64) {
        #pragma unroll
        for (int i = 0; i < 3; ++i) out[(size_t)b * 768 + t + i * 256] = (__hip_bfloat16)0.0f;
        return;
    }
    const float* xr = in + (size_t)b * 197 * 768;
    float v0 = xr[t], v1 = xr[t + 256], v2 = xr[t + 512];
    float s = v0 + v1 + v2;
    float sq = v0*v0 + v1*v1 + v2*v2;
    #pragma unroll
    for (int off = 32; off; off >>= 1) { s += __shfl_xor(s, off); sq += __shfl_xor(sq, off); }
    __shared__ float ss[4], s2[4];
    const int w = t >> 6;
    if ((t & 63) == 0) { ss[w] = s; s2[w] = sq; }
    __syncthreads();
    s  = ss[0] + ss[1] + ss[2] + ss[3];
    sq = s2[0] + s2[1] + s2[2] + s2[3];
    const float inv = 1.0f / 768.0f;
    float mu = s * inv;
    float var = sq * inv - mu * mu;
    float rstd = rsqrtf(var + 1e-5f);
    __hip_bfloat16* o = out + (size_t)b * 768;
    o[t]       = (__hip_bfloat16)((v0 - mu) * rstd * g[t]       + bt[t]);
    o[t + 256] = (__hip_bfloat16)((v1 - mu) * rstd * g[t + 256] + bt[t + 256]);
    o[t + 512] = (__hip_bfloat16)((v2 - mu) * rstd * g[t + 512] + bt[t + 512]);
}

// ---------------------------------------------------------------------------
// z = concat(cls, p_ln) + pos  -> [64,197,768] fp32
// ---------------------------------------------------------------------------
__global__ __launch_bounds__(256) void build_z_k(const float* __restrict__ pln,
                                                 const float* __restrict__ cls,
                                                 const float* __restrict__ pos,
                                                 float* __restrict__ z) {
    size_t idx = (size_t)blockIdx.x * 256 + threadIdx.x;
    int d  = idx % 768;
    size_t tkb = idx / 768;
    int tk = tkb % 197;
    int b  = tkb / 197;
    float v = (tk == 0) ? cls[d] : pln[((size_t)b * 196 + (tk - 1)) * 768 + d];
    z[idx] = v + pos[(size_t)tk * 768 + d];
}

// ---------------------------------------------------------------------------
// Weight convert + transpose: fp32 [K,N] -> bf16 [N,K], z-strided output
// ---------------------------------------------------------------------------
__global__ __launch_bounds__(256) void wconv_k(const float* __restrict__ W,
                                               __hip_bfloat16* __restrict__ Wt,
                                               int K, int N, size_t ostride) {
    __shared__ float tl[64][65];
    const int t = threadIdx.x;
    const int n0 = blockIdx.x * 64, k0 = blockIdx.y * 64;
    const size_t ibase = (size_t)blockIdx.z * K * N;
    const size_t obase = (size_t)blockIdx.z * ostride;
    #pragma unroll
    for (int i = 0; i < 16; ++i) {
        int idx = i * 256 + t;
        int kl = idx >> 6, nl = idx & 63;
        tl[kl][nl] = W[ibase + (size_t)(k0 + kl) * N + n0 + nl];
    }
    __syncthreads();
    #pragma unroll
    for (int i = 0; i < 16; ++i) {
        int idx = i * 256 + t;
        int nl = idx >> 6, kl = idx & 63;
        Wt[obase + (size_t)(n0 + nl) * K + k0 + kl] = (__hip_bfloat16)tl[kl][nl];
    }
}

// ---------------------------------------------------------------------------
// W_head transpose: fp32 [768][1000] -> bf16 [1024][768], pad rows zeroed
// ---------------------------------------------------------------------------
__global__ __launch_bounds__(256) void whT_k(const float* __restrict__ W,
                                             __hip_bfloat16* __restrict__ Wt) {
    __shared__ float tl[64][65];
    const int t = threadIdx.x;
    const int n0 = blockIdx.x * 64, k0 = blockIdx.y * 64;
    #pragma unroll
    for (int i = 0; i < 16; ++i) {
        int idx = i * 256 + t;
        int kl = idx >> 6, nl = idx & 63;
        int n = n0 + nl;
        tl[kl][nl] = (n < 1000) ? W[(size_t)(k0 + kl) * 1000 + n] : 0.f;
    }
    __syncthreads();
    #pragma unroll
    for (int i = 0; i < 16; ++i) {
        int idx = i * 256 + t;
        int nl = idx >> 6, kl = idx & 63;
        Wt[(size_t)(n0 + nl) * 768 + k0 + kl] = (__hip_bfloat16)tl[kl][nl];
    }
}

// ---------------------------------------------------------------------------
// 128x128 bf16 MFMA GEMM, BK=32 (m97-faithful K-step) + XCD swizzle.
// LDS 16 KB -> 8 blocks/CU (32 waves). Swizzle: slot = lgr ^ ((row>>1)&3)
// -> per-wave b128 frag reads hit 8 distinct {parity x slot} positions
// exactly twice = 2-way = free. Used for N=768 GEMMs and the head GEMM.
// ---------------------------------------------------------------------------
template <int EPI, typename OT>
__global__ __launch_bounds__(256) void mgemm_k(const __hip_bfloat16* __restrict__ A,
                                               const __hip_bfloat16* __restrict__ Wt,
                                               const float* __restrict__ bias,
                                               const float* __restrict__ resid,
                                               OT* __restrict__ C,
                                               int M, int N, int K) {
    __shared__ __align__(16) char sA[8192];    // 128 rows x 64B
    __shared__ __align__(16) char sB[8192];
    const int t = threadIdx.x;
    const int lane = t & 63, w = t >> 6;
    const int wr = w >> 1, wc = w & 1;
    const int lrow = lane & 15, lgr = lane >> 4;

    const int gx = gridDim.x;
    const int swz = xcd_swz(blockIdx.y * gx + blockIdx.x, gx * gridDim.y);
    const int bm = (swz / gx) * 128, bn = (swz % gx) * 128;

    const __hip_bfloat16* aSrc[2];
    const __hip_bfloat16* bSrc[2];
    #pragma unroll
    for (int i = 0; i < 2; ++i) {
        int q = t + i * 256;          // 0..511 -> 128 rows x 4 chunks
        int r = q >> 2, c = q & 3;
        int gc = c ^ ((r >> 1) & 3);
        aSrc[i] = A  + (size_t)(bm + r) * K + gc * 8;
        bSrc[i] = Wt + (size_t)(bn + r) * K + gc * 8;
    }

    int aoff[4], boff[4];
    #pragma unroll
    for (int m = 0; m < 4; ++m) {
        int ra = wr * 64 + m * 16 + lrow;
        int rb = wc * 64 + m * 16 + lrow;
        aoff[m] = ra * 64 + ((lgr ^ ((ra >> 1) & 3)) << 4);
        boff[m] = rb * 64 + ((lgr ^ ((rb >> 1) & 3)) << 4);
    }

    fx4 acc[4][4];
    #pragma unroll
    for (int m = 0; m < 4; ++m)
        #pragma unroll
        for (int n = 0; n < 4; ++n)
            #pragma unroll
            for (int e = 0; e < 4; ++e) acc[m][n][e] = 0.f;

    for (int k0 = 0; k0 < K; k0 += 32) {
        #pragma unroll
        for (int i = 0; i < 2; ++i) GLOAD16(aSrc[i] + k0, sA + (t + i * 256) * 16);
        #pragma unroll
        for (int i = 0; i < 2; ++i) GLOAD16(bSrc[i] + k0, sB + (t + i * 256) * 16);
        __syncthreads();
        bfx8 av[4], bv[4];
        #pragma unroll
        for (int m = 0; m < 4; ++m) {
            av[m] = *(const bfx8*)(sA + aoff[m]);
            bv[m] = *(const bfx8*)(sB + boff[m]);
        }
        #pragma unroll
        for (int m = 0; m < 4; ++m)
            #pragma unroll
            for (int n = 0; n < 4; ++n)
                acc[m][n] = __builtin_amdgcn_mfma_f32_16x16x32_bf16(av[m], bv[n], acc[m][n], 0, 0, 0);
        __syncthreads();
    }

    #pragma unroll
    for (int m = 0; m < 4; ++m) {
        #pragma unroll
        for (int n = 0; n < 4; ++n) {
            const int col = bn + wc * 64 + n * 16 + lrow;
            float bv2 = (EPI >= 1) ? bias[col] : 0.f;
            #pragma unroll
            for (int e = 0; e < 4; ++e) {
                const int row = bm + wr * 64 + m * 16 + lgr * 4 + e;
                if (row < M) {
                    float v = acc[m][n][e] + bv2;
                    if (EPI == 2) v = gelu_f(v);
                    if (EPI == 3) v += resid[(size_t)row * N + col];
                    C[(size_t)row * N + col] = (OT)v;
                }
            }
        }
    }
}

// ---------------------------------------------------------------------------
// 256x128 bf16 MFMA GEMM, BK=32, single-buffered 2-barrier (m97 regime).
// 512 thr / 8 waves (4 row x 2 col), LDS 24 KB -> 4 blocks/CU (32 waves,
// wave-capped). __launch_bounds__(512,4) caps VGPR at 128 (R9 spill lesson).
// Swizzle slot = lgr ^ ((row>>1)&3) (2-way, free). XCD swizzle.
// N%128==0, K%32==0, A needs ceil(M/256)*256 readable rows.
// ---------------------------------------------------------------------------
template <int EPI, typename OT>
__global__ __launch_bounds__(512, 4) void mgemm256x128_k(const __hip_bfloat16* __restrict__ A,
                                                         const __hip_bfloat16* __restrict__ Wt,
                                                         const float* __restrict__ bias,
                                                         const float* __restrict__ resid,
                                                         OT* __restrict__ C,
                                                         int M, int N, int K) {
    __shared__ __align__(16) char sA[16384];   // 256 rows x 64B
    __shared__ __align__(16) char sB[8192];    // 128 rows x 64B
    const int t = threadIdx.x;            // 0..511
    const int lane = t & 63, w = t >> 6;  // 8 waves
    const int wr = w >> 1, wc = w & 1;    // 4 x 2 -> 64 x 64 per wave
    const int lrow = lane & 15, lgr = lane >> 4;

    const int gx = gridDim.x;
    const int swz = xcd_swz(blockIdx.y * gx + blockIdx.x, gx * gridDim.y);
    const int bm = (swz / gx) * 256, bn = (swz % gx) * 128;

    const __hip_bfloat16* aSrc[2];
    const __hip_bfloat16* bSrc;
    #pragma unroll
    for (int i = 0; i < 2; ++i) {
        int q = t + i * 512;              // 0..1023 -> 256 rows x 4 chunks
        int r = q >> 2, c = q & 3;
        int gc = c ^ ((r >> 1) & 3);
        aSrc[i] = A + (size_t)(bm + r) * K + gc * 8;
    }
    {
        int q = t;                        // 0..511 -> 128 rows x 4 chunks
        int r = q >> 2, c = q & 3;
        int gc = c ^ ((r >> 1) & 3);
        bSrc = Wt + (size_t)(bn + r) * K + gc * 8;
    }

    int aoff[4], boff[4];
    #pragma unroll
    for (int m = 0; m < 4; ++m) {
        int ra = wr * 64 + m * 16 + lrow;
        int rb = wc * 64 + m * 16 + lrow;
        aoff[m] = ra * 64 + ((lgr ^ ((ra >> 1) & 3)) << 4);
        boff[m] = rb * 64 + ((lgr ^ ((rb >> 1) & 3)) << 4);
    }

    fx4 acc[4][4];
    #pragma unroll
    for (int m = 0; m < 4; ++m)
        #pragma unroll
        for (int n = 0; n < 4; ++n)
            #pragma unroll
            for (int e = 0; e < 4; ++e) acc[m][n][e] = 0.f;

    for (int k0 = 0; k0 < K; k0 += 32) {
        #pragma unroll
        for (int i = 0; i < 2; ++i) GLOAD16(aSrc[i] + k0, sA + (t + i * 512) * 16);
        GLOAD16(bSrc + k0, sB + t * 16);
        __syncthreads();
        bfx8 av[4], bv[4];
        #pragma unroll
        for (int m = 0; m < 4; ++m) {
            av[m] = *(const bfx8*)(sA + aoff[m]);
            bv[m] = *(const bfx8*)(sB + boff[m]);
        }
        #pragma unroll
        for (int m = 0; m < 4; ++m)
            #pragma unroll
            for (int n = 0; n < 4; ++n)
                acc[m][n] = __builtin_amdgcn_mfma_f32_16x16x32_bf16(av[m], bv[n], acc[m][n], 0, 0, 0);
        __syncthreads();
    }

    #pragma unroll
    for (int m = 0; m < 4; ++m) {
        #pragma unroll
        for (int n = 0; n < 4; ++n) {
            const int col = bn + wc * 64 + n * 16 + lrow;
            float bv2 = (EPI >= 1) ? bias[col] : 0.f;
            #pragma unroll
            for (int e = 0; e < 4; ++e) {
                const int row = bm + wr * 64 + m * 16 + lgr * 4 + e;
                if (row < M) {
                    float v = acc[m][n][e] + bv2;
                    if (EPI == 2) v = gelu_f(v);
                    if (EPI == 3) v += resid[(size_t)row * N + col];
                    C[(size_t)row * N + col] = (OT)v;
                }
            }
        }
    }
}

// ---------------------------------------------------------------------------
// MFMA fused attention on fused QKV buffer (row stride 2304).
// ---------------------------------------------------------------------------
__global__ __launch_bounds__(256) void attn_k(const __hip_bfloat16* __restrict__ QKV,
                                              __hip_bfloat16* __restrict__ O) {
    __shared__ __align__(16) char Ks[224 * 128];   // 28672
    __shared__ __align__(16) char VTs[64 * 464];   // 29696
    __shared__ __align__(16) char Ps[4][7424];     // 4 x (16 rows x 464B)

    const int h = blockIdx.x;
    const int b = blockIdx.y;
    const int t = threadIdx.x;
    const int lane = t & 63, w = t >> 6;
    const int rho = lane & 15, g = lane >> 4;
    const size_t base = (size_t)b * NTOK * 2304;
    const int qoff = h * 64, koff = 768 + h * 64, voff = 1536 + h * 64;
    const size_t obase = ((size_t)b * NTOK) * 768 + h * 64;

    #pragma unroll
    for (int i = 0; i < 7; ++i) {
        int q = t + i * 256;            // 0..1791
        int j = q >> 3, c = q & 7;
        int gc = c ^ (j & 7);
        GLOAD16(QKV + base + (size_t)j * 2304 + koff + gc * 8, Ks + q * 16);
    }
    #pragma unroll
    for (int i = 0; i < 7; ++i) {
        int q = t + i * 256;
        int tok = q >> 3, c = q & 7;
        bfx8 vv = {0, 0, 0, 0, 0, 0, 0, 0};
        if (tok < NTOK) vv = *(const bfx8*)(QKV + base + (size_t)tok * 2304 + voff + c * 8);
        #pragma unroll
        for (int u = 0; u < 8; ++u)
            *(unsigned short*)(VTs + (c * 8 + u) * 464 + tok * 2) = (unsigned short)vv[u];
    }
    __syncthreads();

    char* Pw = Ps[w];

    for (int qt = w; qt < 13; qt += 4) {
        const int q0 = qt * 16;
        fx4 s[13];
        #pragma unroll
        for (int nt = 0; nt < 13; ++nt)
            #pragma unroll
            for (int e = 0; e < 4; ++e) s[nt][e] = 0.f;
        #pragma unroll
        for (int ks = 0; ks < 2; ++ks) {
            bfx8 av = *(const bfx8*)(QKV + base + (size_t)(q0 + rho) * 2304 + qoff + ks * 32 + g * 8);
            #pragma unroll
            for (int nt = 0; nt < 13; ++nt) {
                int r = nt * 16 + rho;
                bfx8 bv = *(const bfx8*)(Ks + r * 128 + (((ks * 4 + g) ^ (r & 7)) << 4));
                s[nt] = __builtin_amdgcn_mfma_f32_16x16x32_bf16(av, bv, s[nt], 0, 0, 0);
            }
        }
        float mx[4] = {-1e30f, -1e30f, -1e30f, -1e30f};
        #pragma unroll
        for (int nt = 0; nt < 13; ++nt) {
            #pragma unroll
            for (int e = 0; e < 4; ++e) {
                float v = s[nt][e] * 0.125f;
                if (nt == 12 && rho >= 5) v = -1e30f;
                s[nt][e] = v;
                mx[e] = fmaxf(mx[e], v);
            }
        }
        #pragma unroll
        for (int off = 1; off < 16; off <<= 1)
            #pragma unroll
            for (int e = 0; e < 4; ++e) mx[e] = fmaxf(mx[e], __shfl_xor(mx[e], off));
        float sm[4] = {0.f, 0.f, 0.f, 0.f};
        #pragma unroll
        for (int nt = 0; nt < 13; ++nt)
            #pragma unroll
            for (int e = 0; e < 4; ++e) {
                float p = __expf(s[nt][e] - mx[e]);
                s[nt][e] = p;
                sm[e] += p;
            }
        #pragma unroll
        for (int off = 1; off < 16; off <<= 1)
            #pragma unroll
            for (int e = 0; e < 4; ++e) sm[e] += __shfl_xor(sm[e], off);
        float inv[4];
        #pragma unroll
        for (int e = 0; e < 4; ++e) inv[e] = 1.0f / sm[e];

        #pragma unroll
        for (int nt = 0; nt < 13; ++nt)
            #pragma unroll
            for (int e = 0; e < 4; ++e) {
                int row = g * 4 + e;
                int col = nt * 16 + rho;
                *(__hip_bfloat16*)(Pw + row * 464 + col * 2) =
                    (__hip_bfloat16)(s[nt][e] * inv[e]);
            }
        #pragma unroll
        for (int e = 0; e < 4; ++e)
            *(__hip_bfloat16*)(Pw + (g * 4 + e) * 464 + (208 + rho) * 2) = (__hip_bfloat16)0.0f;

        __builtin_amdgcn_sched_barrier(0);
        asm volatile("s_waitcnt lgkmcnt(0)" ::: "memory");
        __builtin_amdgcn_sched_barrier(0);

        #pragma unroll
        for (int dt = 0; dt < 4; ++dt) {
            fx4 o;
            #pragma unroll
            for (int e = 0; e < 4; ++e) o[e] = 0.f;
            #pragma unroll
            for (int ks = 0; ks < 7; ++ks) {
                bfx8 pa = *(const bfx8*)(Pw + rho * 464 + (ks * 4 + g) * 16);
                bfx8 bv = *(const bfx8*)(VTs + (dt * 16 + rho) * 464 + (ks * 4 + g) * 16);
                o = __builtin_amdgcn_mfma_f32_16x16x32_bf16(pa, bv, o, 0, 0, 0);
            }
            #pragma unroll
            for (int e = 0; e < 4; ++e) {
                int qrow = q0 + g * 4 + e;
                if (qrow < NTOK)
                    O[obase + (size_t)qrow * 768 + dt * 16 + rho] = (__hip_bfloat16)o[e];
            }
        }
    }
}

// ---------------------------------------------------------------------------
// Head softmax: out[b,:] = softmax(logits[b,:1000] + b_head)
// ---------------------------------------------------------------------------
__global__ __launch_bounds__(256) void shead_k(const float* __restrict__ logits,
                                               const float* __restrict__ bh,
                                               float* __restrict__ out) {
    const int b = blockIdx.x;
    const int t = threadIdx.x;
    __shared__ float lg[1000];
    __shared__ float red[4];

    for (int c = t; c < 1000; c += 256) lg[c] = logits[(size_t)b * 1024 + c] + bh[c];
    __syncthreads();

    float m = -1e30f;
    for (int c = t; c < 1000; c += 256) m = fmaxf(m, lg[c]);
    #pragma unroll
    for (int off = 32; off; off >>= 1) m = fmaxf(m, __shfl_xor(m, off));
    if ((t & 63) == 0) red[t >> 6] = m;
    __syncthreads();
    m = fmaxf(fmaxf(red[0], red[1]), fmaxf(red[2], red[3]));
    __syncthreads();

    float sum = 0.f;
    for (int c = t; c < 1000; c += 256) sum += __expf(lg[c] - m);
    #pragma unroll
    for (int off = 32; off; off >>= 1) sum += __shfl_xor(sum, off);
    if ((t & 63) == 0) red[t >> 6] = sum;
    __syncthreads();
    sum = red[0] + red[1] + red[2] + red[3];
    const float invs = 1.0f / sum;
    for (int c = t; c < 1000; c += 256) out[(size_t)b * 1000 + c] = __expf(lg[c] - m) * invs;
}

// ---------------------------------------------------------------------------
// Driver
// ---------------------------------------------------------------------------
extern "C" void kernel_launch(void* const* d_in, const int* in_sizes, int n_in,
                              void* d_out, int out_size, void* d_ws, size_t ws_size,
                              hipStream_t stream) {
    const float* x        = (const float*)d_in[0];
    const float* ln_p_g   = (const float*)d_in[1];
    const float* ln_p_b   = (const float*)d_in[2];
    const float* W_patch  = (const float*)d_in[3];
    const float* b_patch  = (const float*)d_in[4];
    const float* ln_e_g   = (const float*)d_in[5];
    const float* ln_e_b   = (const float*)d_in[6];
    const float* pos_emb  = (const float*)d_in[7];
    const float* cls_tok  = (const float*)d_in[8];
    const float* ln_a_g   = (const float*)d_in[9];
    const float* ln_a_b   = (const float*)d_in[10];
    const float* Wq       = (const float*)d_in[11];
    const float* Wk       = (const float*)d_in[12];
    const float* Wv       = (const float*)d_in[13];
    const float* Wo       = (const float*)d_in[14];
    const float* bo       = (const float*)d_in[15];
    const float* ln_f_g   = (const float*)d_in[16];
    const float* ln_f_b   = (const float*)d_in[17];
    const float* W1       = (const float*)d_in[18];
    const float* b1       = (const float*)d_in[19];
    const float* W2       = (const float*)d_in[20];
    const float* b2       = (const float*)d_in[21];
    const float* ln_out_g = (const float*)d_in[22];
    const float* ln_out_b = (const float*)d_in[23];
    const float* W_head   = (const float*)d_in[24];
    const float* b_head   = (const float*)d_in[25];

    typedef __hip_bfloat16 bf;
    const int M  = 12608;               // 64*197
    const int MP = 12800;               // padded to 50*256
    char* p = (char*)d_ws;

    float* Z   = (float*)p;            p += (size_t)MP * 768 * 4;      // fp32 residual
    bf* XA     = (bf*)p;               p += (size_t)MP * 768 * 2;      // LN out (bf16)
    bf* QKV    = (bf*)p;               p += (size_t)MP * 2304 * 2;     // fused q,k,v
    bf* OB     = (bf*)p;               p += (size_t)MP * 768 * 2;
    char* FFHc = p;                    p += (size_t)MP * 3072 * 2;     // bf16 GELU buf
    bf* FFH    = (bf*)FFHc;
    float* PE  = (float*)FFHc;                                          // alias: patch-embed fp32
    float* E2  = (float*)(FFHc + (size_t)MP * 768 * 4);                 // alias: ln_e out fp32
    bf* WQKVT  = (bf*)p;               p += (size_t)12 * 2304 * 768 * 2;
    bf* WoT    = (bf*)p;               p += (size_t)12 * 768 * 768 * 2;
    bf* W1T    = (bf*)p;               p += (size_t)12 * 3072 * 768 * 2;
    bf* W2T    = (bf*)p;               p += (size_t)12 * 768 * 3072 * 2;
    bf* WpT    = (bf*)p;               p += (size_t)768 * 768 * 2;
    bf* WhT    = (bf*)p;               p += (size_t)1024 * 768 * 2;
    bf* CLS    = (bf*)p;               p += (size_t)128 * 768 * 2;
    float* LOG = (float*)p;            p += (size_t)64 * 1024 * 4;

    const size_t QKVS = (size_t)2304 * 768;

    // weight convert + transpose (every launch)
    wconv_k<<<dim3(12, 12, 12), 256, 0, stream>>>(Wq, WQKVT,             768, 768,  QKVS);
    wconv_k<<<dim3(12, 12, 12), 256, 0, stream>>>(Wk, WQKVT + 768 * 768, 768, 768,  QKVS);
    wconv_k<<<dim3(12, 12, 12), 256, 0, stream>>>(Wv, WQKVT + 1536 * 768,768, 768,  QKVS);
    wconv_k<<<dim3(12, 12, 12), 256, 0, stream>>>(Wo, WoT,  768, 768,  (size_t)768 * 768);
    wconv_k<<<dim3(48, 12, 12), 256, 0, stream>>>(W1, W1T,  768, 3072, (size_t)3072 * 768);
    wconv_k<<<dim3(12, 48, 12), 256, 0, stream>>>(W2, W2T,  3072, 768, (size_t)768 * 3072);
    wconv_k<<<dim3(12, 12, 1),  256, 0, stream>>>(W_patch, WpT, 768, 768, 0);
    whT_k  <<<dim3(16, 12),     256, 0, stream>>>(W_head, WhT);

    // patch embed pipeline
    patch_ln_k<<<12544, 256, 0, stream>>>(x, XA, ln_p_g, ln_p_b);
    mgemm_k<1, float><<<dim3(6, 98), 256, 0, stream>>>(XA, WpT, b_patch, nullptr, PE, 12544, 768, 768);
    ln_k<float><<<12544, 256, 0, stream>>>(PE, E2, ln_e_g, ln_e_b);
    build_z_k<<<37824, 256, 0, stream>>>(E2, cls_tok, pos_emb, Z);

    for (int i = 0; i < 12; ++i) {
        bf* WQKVT_i = WQKVT + (size_t)i * QKVS;
        bf* WoT_i   = WoT + (size_t)i * 768 * 768;
        bf* W1T_i   = W1T + (size_t)i * 3072 * 768;
        bf* W2T_i   = W2T + (size_t)i * 768 * 3072;

        ln_k<bf><<<M, 256, 0, stream>>>(Z, XA, ln_a_g + (size_t)i * 768, ln_a_b + (size_t)i * 768);
        mgemm256x128_k<0, bf><<<dim3(18, 50), 512, 0, stream>>>(XA, WQKVT_i, nullptr, nullptr, QKV, M, 2304, 768);
        attn_k<<<dim3(12, 64), 256, 0, stream>>>(QKV, OB);
        mgemm_k<3, float><<<dim3(6, 99), 256, 0, stream>>>(OB, WoT_i, bo + (size_t)i * 768, Z, Z, M, 768, 768);
        ln_k<bf><<<M, 256, 0, stream>>>(Z, XA, ln_f_g + (size_t)i * 768, ln_f_b + (size_t)i * 768);
        mgemm256x128_k<2, bf><<<dim3(24, 50), 512, 0, stream>>>(XA, W1T_i, b1 + (size_t)i * 3072, nullptr, FFH, M, 3072, 768);
        mgemm_k<3, float><<<dim3(6, 99), 256, 0, stream>>>(FFH, W2T_i, b2 + (size_t)i * 768, Z, Z, M, 768, 3072);
    }

    // head: LN(CLS rows) -> logits GEMM (128^2 kernel) -> softmax
    ln_cls_k<<<128, 256, 0, stream>>>(Z, CLS, ln_out_g, ln_out_b);
    mgemm_k<0, float><<<dim3(8, 1), 256, 0, stream>>>(CLS, WhT, nullptr, nullptr, LOG, 64, 1024, 768);
    shead_k<<<64, 256, 0, stream>>>(LOG, b_head, (float*)d_out);
}

// Round 13
// 4600.840 us; speedup vs baseline: 1.1392x; 1.0790x over previous
//
#include <hip/hip_runtime.h>
#include <hip/hip_bf16.h>
#include <math.h>

#define NTOK 197

typedef __attribute__((ext_vector_type(8))) short bfx8;
typedef __attribute__((ext_vector_type(4))) float fx4;

#define GLOAD16(gsrc, ldst) __builtin_amdgcn_global_load_lds( \
    (const __attribute__((address_space(1))) void*)(gsrc),    \
    (__attribute__((address_space(3))) void*)(ldst), 16, 0, 0)

__device__ __forceinline__ float gelu_f(float x) {
    return 0.5f * x * (1.0f + erff(x * 0.70710678118654752f));
}

// bijective XCD swizzle (T1, m204): contiguous chunk of blocks per XCD
__device__ __forceinline__ int xcd_swz(int orig, int nwg) {
    const int q8 = nwg >> 3, r8 = nwg & 7;
    const int xcd = orig & 7, idx8 = orig >> 3;
    return (xcd < r8 ? xcd * (q8 + 1) : r8 * (q8 + 1) + (xcd - r8) * q8) + idx8;
}

// ---------------------------------------------------------------------------
// Patch extraction + LayerNorm -> bf16. Coalesced float4 loads staged via LDS.
// ---------------------------------------------------------------------------
__global__ __launch_bounds__(256) void patch_ln_k(const float* __restrict__ x,
                                                  __hip_bfloat16* __restrict__ out,
                                                  const float* __restrict__ g,
                                                  const float* __restrict__ bt) {
    const int r = blockIdx.x;          // 0..12543
    const int t = threadIdx.x;
    const int b = r / 196, p = r % 196;
    const int ph = p / 14, pw = p % 14;

    __shared__ float px[768];
    if (t < 192) {
        int rr = t >> 2, seg = t & 3;
        int c = rr >> 4, h1 = rr & 15;
        const float* src = x + (((size_t)b * 3 + c) * 224 + (ph * 16 + h1)) * 224
                             + pw * 16 + seg * 4;
        float4 v4 = *(const float4*)src;
        px[(h1 * 16 + seg * 4 + 0) * 3 + c] = v4.x;
        px[(h1 * 16 + seg * 4 + 1) * 3 + c] = v4.y;
        px[(h1 * 16 + seg * 4 + 2) * 3 + c] = v4.z;
        px[(h1 * 16 + seg * 4 + 3) * 3 + c] = v4.w;
    }
    __syncthreads();

    float v[3];
    #pragma unroll
    for (int i = 0; i < 3; ++i) v[i] = px[t + i * 256];
    float s = v[0] + v[1] + v[2];
    float sq = v[0]*v[0] + v[1]*v[1] + v[2]*v[2];
    #pragma unroll
    for (int off = 32; off; off >>= 1) { s += __shfl_xor(s, off); sq += __shfl_xor(sq, off); }
    __shared__ float ss[4], s2[4];
    const int w = t >> 6;
    if ((t & 63) == 0) { ss[w] = s; s2[w] = sq; }
    __syncthreads();
    s  = ss[0] + ss[1] + ss[2] + ss[3];
    sq = s2[0] + s2[1] + s2[2] + s2[3];
    const float inv = 1.0f / 768.0f;
    float mu = s * inv;
    float var = sq * inv - mu * mu;
    float rstd = rsqrtf(var + 1e-5f);
    __hip_bfloat16* o = out + (size_t)r * 768;
    #pragma unroll
    for (int i = 0; i < 3; ++i) {
        int d = t + i * 256;
        o[d] = (__hip_bfloat16)((v[i] - mu) * rstd * g[d] + bt[d]);
    }
}

// ---------------------------------------------------------------------------
// Row LayerNorm over 768 fp32 -> OT
// ---------------------------------------------------------------------------
template <typename OT>
__global__ __launch_bounds__(256) void ln_k(const float* __restrict__ in,
                                            OT* __restrict__ out,
                                            const float* __restrict__ g,
                                            const float* __restrict__ bt) {
    const int r = blockIdx.x;
    const int t = threadIdx.x;
    const float* xr = in + (size_t)r * 768;
    float v0 = xr[t], v1 = xr[t + 256], v2 = xr[t + 512];
    float s = v0 + v1 + v2;
    float sq = v0*v0 + v1*v1 + v2*v2;
    #pragma unroll
    for (int off = 32; off; off >>= 1) { s += __shfl_xor(s, off); sq += __shfl_xor(sq, off); }
    __shared__ float ss[4], s2[4];
    const int w = t >> 6;
    if ((t & 63) == 0) { ss[w] = s; s2[w] = sq; }
    __syncthreads();
    s  = ss[0] + ss[1] + ss[2] + ss[3];
    sq = s2[0] + s2[1] + s2[2] + s2[3];
    const float inv = 1.0f / 768.0f;
    float mu = s * inv;
    float var = sq * inv - mu * mu;
    float rstd = rsqrtf(var + 1e-5f);
    OT* o = out + (size_t)r * 768;
    o[t]       = (OT)((v0 - mu) * rstd * g[t]       + bt[t]);
    o[t + 256] = (OT)((v1 - mu) * rstd * g[t + 256] + bt[t + 256]);
    o[t + 512] = (OT)((v2 - mu) * rstd * g[t + 512] + bt[t + 512]);
}

// ---------------------------------------------------------------------------
// LN of CLS rows only -> bf16 [128][768] (rows 64..127 zeroed)
// ---------------------------------------------------------------------------
__global__ __launch_bounds__(256) void ln_cls_k(const float* __restrict__ in,
                                                __hip_bfloat16* __restrict__ out,
                                                const float* __restrict__ g,
                                                const float* __restrict__ bt) {
    const int b = blockIdx.x;   // 0..127
    const int t = threadIdx.x;
    if (b >= 64) {
        #pragma unroll
        for (int i = 0; i < 3; ++i) out[(size_t)b * 768 + t + i * 256] = (__hip_bfloat16)0.0f;
        return;
    }
    const float* xr = in + (size_t)b * 197 * 768;
    float v0 = xr[t], v1 = xr[t + 256], v2 = xr[t + 512];
    float s = v0 + v1 + v2;
    float sq = v0*v0 + v1*v1 + v2*v2;
    #pragma unroll
    for (int off = 32; off; off >>= 1) { s += __shfl_xor(s, off); sq += __shfl_xor(sq, off); }
    __shared__ float ss[4], s2[4];
    const int w = t >> 6;
    if ((t & 63) == 0) { ss[w] = s; s2[w] = sq; }
    __syncthreads();
    s  = ss[0] + ss[1] + ss[2] + ss[3];
    sq = s2[0] + s2[1] + s2[2] + s2[3];
    const float inv = 1.0f / 768.0f;
    float mu = s * inv;
    float var = sq * inv - mu * mu;
    float rstd = rsqrtf(var + 1e-5f);
    __hip_bfloat16* o = out + (size_t)b * 768;
    o[t]       = (__hip_bfloat16)((v0 - mu) * rstd * g[t]       + bt[t]);
    o[t + 256] = (__hip_bfloat16)((v1 - mu) * rstd * g[t + 256] + bt[t + 256]);
    o[t + 512] = (__hip_bfloat16)((v2 - mu) * rstd * g[t + 512] + bt[t + 512]);
}

// ---------------------------------------------------------------------------
// z = concat(cls, p_ln) + pos  -> [64,197,768] fp32
// ---------------------------------------------------------------------------
__global__ __launch_bounds__(256) void build_z_k(const float* __restrict__ pln,
                                                 const float* __restrict__ cls,
                                                 const float* __restrict__ pos,
                                                 float* __restrict__ z) {
    size_t idx = (size_t)blockIdx.x * 256 + threadIdx.x;
    int d  = idx % 768;
    size_t tkb = idx / 768;
    int tk = tkb % 197;
    int b  = tkb / 197;
    float v = (tk == 0) ? cls[d] : pln[((size_t)b * 196 + (tk - 1)) * 768 + d];
    z[idx] = v + pos[(size_t)tk * 768 + d];
}

// ---------------------------------------------------------------------------
// Weight convert + transpose: fp32 [K,N] -> bf16 [N,K], z-strided output
// ---------------------------------------------------------------------------
__global__ __launch_bounds__(256) void wconv_k(const float* __restrict__ W,
                                               __hip_bfloat16* __restrict__ Wt,
                                               int K, int N, size_t ostride) {
    __shared__ float tl[64][65];
    const int t = threadIdx.x;
    const int n0 = blockIdx.x * 64, k0 = blockIdx.y * 64;
    const size_t ibase = (size_t)blockIdx.z * K * N;
    const size_t obase = (size_t)blockIdx.z * ostride;
    #pragma unroll
    for (int i = 0; i < 16; ++i) {
        int idx = i * 256 + t;
        int kl = idx >> 6, nl = idx & 63;
        tl[kl][nl] = W[ibase + (size_t)(k0 + kl) * N + n0 + nl];
    }
    __syncthreads();
    #pragma unroll
    for (int i = 0; i < 16; ++i) {
        int idx = i * 256 + t;
        int nl = idx >> 6, kl = idx & 63;
        Wt[obase + (size_t)(n0 + nl) * K + k0 + kl] = (__hip_bfloat16)tl[kl][nl];
    }
}

// ---------------------------------------------------------------------------
// W_head transpose: fp32 [768][1000] -> bf16 [1024][768], pad rows zeroed
// ---------------------------------------------------------------------------
__global__ __launch_bounds__(256) void whT_k(const float* __restrict__ W,
                                             __hip_bfloat16* __restrict__ Wt) {
    __shared__ float tl[64][65];
    const int t = threadIdx.x;
    const int n0 = blockIdx.x * 64, k0 = blockIdx.y * 64;
    #pragma unroll
    for (int i = 0; i < 16; ++i) {
        int idx = i * 256 + t;
        int kl = idx >> 6, nl = idx & 63;
        int n = n0 + nl;
        tl[kl][nl] = (n < 1000) ? W[(size_t)(k0 + kl) * 1000 + n] : 0.f;
    }
    __syncthreads();
    #pragma unroll
    for (int i = 0; i < 16; ++i) {
        int idx = i * 256 + t;
        int nl = idx >> 6, kl = idx & 63;
        Wt[(size_t)(n0 + nl) * 768 + k0 + kl] = (__hip_bfloat16)tl[kl][nl];
    }
}

// ---------------------------------------------------------------------------
// 128x128 bf16 MFMA GEMM, BK=64 (round-5/10 known-good) + XCD swizzle.
// Used for the small head GEMM only now.
// ---------------------------------------------------------------------------
template <int EPI, typename OT>
__global__ __launch_bounds__(256) void mgemm_k(const __hip_bfloat16* __restrict__ A,
                                               const __hip_bfloat16* __restrict__ Wt,
                                               const float* __restrict__ bias,
                                               const float* __restrict__ resid,
                                               OT* __restrict__ C,
                                               int M, int N, int K) {
    __shared__ __align__(16) char sA[16384];
    __shared__ __align__(16) char sB[16384];
    const int t = threadIdx.x;
    const int lane = t & 63, w = t >> 6;
    const int wr = w >> 1, wc = w & 1;
    const int lrow = lane & 15, lgr = lane >> 4;

    const int gx = gridDim.x;
    const int swz = xcd_swz(blockIdx.y * gx + blockIdx.x, gx * gridDim.y);
    const int bm = (swz / gx) * 128, bn = (swz % gx) * 128;

    const __hip_bfloat16* aSrc[4];
    const __hip_bfloat16* bSrc[4];
    #pragma unroll
    for (int i = 0; i < 4; ++i) {
        int q = t + i * 256;          // 0..1023
        int r = q >> 3, c = q & 7;
        int gc = c ^ (r & 7);
        aSrc[i] = A  + (size_t)(bm + r) * K + gc * 8;
        bSrc[i] = Wt + (size_t)(bn + r) * K + gc * 8;
    }

    int aoff[4][2], boff[4][2];
    #pragma unroll
    for (int m = 0; m < 4; ++m) {
        int ra = wr * 64 + m * 16 + lrow;
        int rb = wc * 64 + m * 16 + lrow;
        #pragma unroll
        for (int ks = 0; ks < 2; ++ks) {
            aoff[m][ks] = ra * 128 + (((ks * 4 + lgr) ^ (ra & 7)) << 4);
            boff[m][ks] = rb * 128 + (((ks * 4 + lgr) ^ (rb & 7)) << 4);
        }
    }

    fx4 acc[4][4];
    #pragma unroll
    for (int m = 0; m < 4; ++m)
        #pragma unroll
        for (int n = 0; n < 4; ++n)
            #pragma unroll
            for (int e = 0; e < 4; ++e) acc[m][n][e] = 0.f;

    for (int k0 = 0; k0 < K; k0 += 64) {
        #pragma unroll
        for (int i = 0; i < 4; ++i) GLOAD16(aSrc[i] + k0, sA + (t + i * 256) * 16);
        #pragma unroll
        for (int i = 0; i < 4; ++i) GLOAD16(bSrc[i] + k0, sB + (t + i * 256) * 16);
        __syncthreads();
        #pragma unroll
        for (int ks = 0; ks < 2; ++ks) {
            bfx8 av[4], bv[4];
            #pragma unroll
            for (int m = 0; m < 4; ++m) {
                av[m] = *(const bfx8*)(sA + aoff[m][ks]);
                bv[m] = *(const bfx8*)(sB + boff[m][ks]);
            }
            #pragma unroll
            for (int m = 0; m < 4; ++m)
                #pragma unroll
                for (int n = 0; n < 4; ++n)
                    acc[m][n] = __builtin_amdgcn_mfma_f32_16x16x32_bf16(av[m], bv[n], acc[m][n], 0, 0, 0);
        }
        __syncthreads();
    }

    #pragma unroll
    for (int m = 0; m < 4; ++m) {
        #pragma unroll
        for (int n = 0; n < 4; ++n) {
            const int col = bn + wc * 64 + n * 16 + lrow;
            float bv2 = (EPI >= 1) ? bias[col] : 0.f;
            #pragma unroll
            for (int e = 0; e < 4; ++e) {
                const int row = bm + wr * 64 + m * 16 + lgr * 4 + e;
                if (row < M) {
                    float v = acc[m][n][e] + bv2;
                    if (EPI == 2) v = gelu_f(v);
                    if (EPI == 3) v += resid[(size_t)row * N + col];
                    C[(size_t)row * N + col] = (OT)v;
                }
            }
        }
    }
}

// ---------------------------------------------------------------------------
// 256x128 bf16 MFMA GEMM, BK=64 — the round-10 proven workhorse.
// 512 thr / 8 waves (4 row x 2 col), 48 KB LDS -> 3 blocks/CU.
// __launch_bounds__(512, 4): VGPR cap 128 (no spill; R9's (512,6) spilled).
// Used for ALL transformer GEMMs (QKV, Wo, FF1, W2) + patch embed.
// N%128==0, K%64==0, A needs ceil(M/256)*256 readable rows.
// ---------------------------------------------------------------------------
template <int EPI, typename OT>
__global__ __launch_bounds__(512, 4) void mgemm256x128_k(const __hip_bfloat16* __restrict__ A,
                                                         const __hip_bfloat16* __restrict__ Wt,
                                                         const float* __restrict__ bias,
                                                         const float* __restrict__ resid,
                                                         OT* __restrict__ C,
                                                         int M, int N, int K) {
    __shared__ __align__(16) char sA[32768];   // 256 rows x 128B
    __shared__ __align__(16) char sB[16384];   // 128 rows x 128B
    const int t = threadIdx.x;            // 0..511
    const int lane = t & 63, w = t >> 6;  // 8 waves
    const int wr = w >> 1, wc = w & 1;    // 4 x 2 -> 64 x 64 per wave
    const int lrow = lane & 15, lgr = lane >> 4;

    const int gx = gridDim.x;
    const int swz = xcd_swz(blockIdx.y * gx + blockIdx.x, gx * gridDim.y);
    const int bm = (swz / gx) * 256, bn = (swz % gx) * 128;

    const __hip_bfloat16* aSrc[4];
    const __hip_bfloat16* bSrc[2];
    #pragma unroll
    for (int i = 0; i < 4; ++i) {
        int q = t + i * 512;              // 0..2047 -> 256 rows x 8 chunks
        int r = q >> 3, c = q & 7;
        int gc = c ^ (r & 7);
        aSrc[i] = A + (size_t)(bm + r) * K + gc * 8;
    }
    #pragma unroll
    for (int i = 0; i < 2; ++i) {
        int q = t + i * 512;              // 0..1023 -> 128 rows x 8 chunks
        int r = q >> 3, c = q & 7;
        int gc = c ^ (r & 7);
        bSrc[i] = Wt + (size_t)(bn + r) * K + gc * 8;
    }

    int aoff[4][2], boff[4][2];
    #pragma unroll
    for (int m = 0; m < 4; ++m) {
        int ra = wr * 64 + m * 16 + lrow;
        int rb = wc * 64 + m * 16 + lrow;
        #pragma unroll
        for (int ks = 0; ks < 2; ++ks) {
            aoff[m][ks] = ra * 128 + (((ks * 4 + lgr) ^ (ra & 7)) << 4);
            boff[m][ks] = rb * 128 + (((ks * 4 + lgr) ^ (rb & 7)) << 4);
        }
    }

    fx4 acc[4][4];
    #pragma unroll
    for (int m = 0; m < 4; ++m)
        #pragma unroll
        for (int n = 0; n < 4; ++n)
            #pragma unroll
            for (int e = 0; e < 4; ++e) acc[m][n][e] = 0.f;

    for (int k0 = 0; k0 < K; k0 += 64) {
        #pragma unroll
        for (int i = 0; i < 4; ++i) GLOAD16(aSrc[i] + k0, sA + (t + i * 512) * 16);
        #pragma unroll
        for (int i = 0; i < 2; ++i) GLOAD16(bSrc[i] + k0, sB + (t + i * 512) * 16);
        __syncthreads();
        #pragma unroll
        for (int ks = 0; ks < 2; ++ks) {
            bfx8 av[4], bv[4];
            #pragma unroll
            for (int m = 0; m < 4; ++m) {
                av[m] = *(const bfx8*)(sA + aoff[m][ks]);
                bv[m] = *(const bfx8*)(sB + boff[m][ks]);
            }
            #pragma unroll
            for (int m = 0; m < 4; ++m)
                #pragma unroll
                for (int n = 0; n < 4; ++n)
                    acc[m][n] = __builtin_amdgcn_mfma_f32_16x16x32_bf16(av[m], bv[n], acc[m][n], 0, 0, 0);
        }
        __syncthreads();
    }

    #pragma unroll
    for (int m = 0; m < 4; ++m) {
        #pragma unroll
        for (int n = 0; n < 4; ++n) {
            const int col = bn + wc * 64 + n * 16 + lrow;
            float bv2 = (EPI >= 1) ? bias[col] : 0.f;
            #pragma unroll
            for (int e = 0; e < 4; ++e) {
                const int row = bm + wr * 64 + m * 16 + lgr * 4 + e;
                if (row < M) {
                    float v = acc[m][n][e] + bv2;
                    if (EPI == 2) v = gelu_f(v);
                    if (EPI == 3) v += resid[(size_t)row * N + col];
                    C[(size_t)row * N + col] = (OT)v;
                }
            }
        }
    }
}

// ---------------------------------------------------------------------------
// MFMA fused attention on fused QKV buffer (row stride 2304).
// ---------------------------------------------------------------------------
__global__ __launch_bounds__(256) void attn_k(const __hip_bfloat16* __restrict__ QKV,
                                              __hip_bfloat16* __restrict__ O) {
    __shared__ __align__(16) char Ks[224 * 128];   // 28672
    __shared__ __align__(16) char VTs[64 * 464];   // 29696
    __shared__ __align__(16) char Ps[4][7424];     // 4 x (16 rows x 464B)

    const int h = blockIdx.x;
    const int b = blockIdx.y;
    const int t = threadIdx.x;
    const int lane = t & 63, w = t >> 6;
    const int rho = lane & 15, g = lane >> 4;
    const size_t base = (size_t)b * NTOK * 2304;
    const int qoff = h * 64, koff = 768 + h * 64, voff = 1536 + h * 64;
    const size_t obase = ((size_t)b * NTOK) * 768 + h * 64;

    #pragma unroll
    for (int i = 0; i < 7; ++i) {
        int q = t + i * 256;            // 0..1791
        int j = q >> 3, c = q & 7;
        int gc = c ^ (j & 7);
        GLOAD16(QKV + base + (size_t)j * 2304 + koff + gc * 8, Ks + q * 16);
    }
    #pragma unroll
    for (int i = 0; i < 7; ++i) {
        int q = t + i * 256;
        int tok = q >> 3, c = q & 7;
        bfx8 vv = {0, 0, 0, 0, 0, 0, 0, 0};
        if (tok < NTOK) vv = *(const bfx8*)(QKV + base + (size_t)tok * 2304 + voff + c * 8);
        #pragma unroll
        for (int u = 0; u < 8; ++u)
            *(unsigned short*)(VTs + (c * 8 + u) * 464 + tok * 2) = (unsigned short)vv[u];
    }
    __syncthreads();

    char* Pw = Ps[w];

    for (int qt = w; qt < 13; qt += 4) {
        const int q0 = qt * 16;
        fx4 s[13];
        #pragma unroll
        for (int nt = 0; nt < 13; ++nt)
            #pragma unroll
            for (int e = 0; e < 4; ++e) s[nt][e] = 0.f;
        #pragma unroll
        for (int ks = 0; ks < 2; ++ks) {
            bfx8 av = *(const bfx8*)(QKV + base + (size_t)(q0 + rho) * 2304 + qoff + ks * 32 + g * 8);
            #pragma unroll
            for (int nt = 0; nt < 13; ++nt) {
                int r = nt * 16 + rho;
                bfx8 bv = *(const bfx8*)(Ks + r * 128 + (((ks * 4 + g) ^ (r & 7)) << 4));
                s[nt] = __builtin_amdgcn_mfma_f32_16x16x32_bf16(av, bv, s[nt], 0, 0, 0);
            }
        }
        float mx[4] = {-1e30f, -1e30f, -1e30f, -1e30f};
        #pragma unroll
        for (int nt = 0; nt < 13; ++nt) {
            #pragma unroll
            for (int e = 0; e < 4; ++e) {
                float v = s[nt][e] * 0.125f;
                if (nt == 12 && rho >= 5) v = -1e30f;
                s[nt][e] = v;
                mx[e] = fmaxf(mx[e], v);
            }
        }
        #pragma unroll
        for (int off = 1; off < 16; off <<= 1)
            #pragma unroll
            for (int e = 0; e < 4; ++e) mx[e] = fmaxf(mx[e], __shfl_xor(mx[e], off));
        float sm[4] = {0.f, 0.f, 0.f, 0.f};
        #pragma unroll
        for (int nt = 0; nt < 13; ++nt)
            #pragma unroll
            for (int e = 0; e < 4; ++e) {
                float p = __expf(s[nt][e] - mx[e]);
                s[nt][e] = p;
                sm[e] += p;
            }
        #pragma unroll
        for (int off = 1; off < 16; off <<= 1)
            #pragma unroll
            for (int e = 0; e < 4; ++e) sm[e] += __shfl_xor(sm[e], off);
        float inv[4];
        #pragma unroll
        for (int e = 0; e < 4; ++e) inv[e] = 1.0f / sm[e];

        #pragma unroll
        for (int nt = 0; nt < 13; ++nt)
            #pragma unroll
            for (int e = 0; e < 4; ++e) {
                int row = g * 4 + e;
                int col = nt * 16 + rho;
                *(__hip_bfloat16*)(Pw + row * 464 + col * 2) =
                    (__hip_bfloat16)(s[nt][e] * inv[e]);
            }
        #pragma unroll
        for (int e = 0; e < 4; ++e)
            *(__hip_bfloat16*)(Pw + (g * 4 + e) * 464 + (208 + rho) * 2) = (__hip_bfloat16)0.0f;

        __builtin_amdgcn_sched_barrier(0);
        asm volatile("s_waitcnt lgkmcnt(0)" ::: "memory");
        __builtin_amdgcn_sched_barrier(0);

        #pragma unroll
        for (int dt = 0; dt < 4; ++dt) {
            fx4 o;
            #pragma unroll
            for (int e = 0; e < 4; ++e) o[e] = 0.f;
            #pragma unroll
            for (int ks = 0; ks < 7; ++ks) {
                bfx8 pa = *(const bfx8*)(Pw + rho * 464 + (ks * 4 + g) * 16);
                bfx8 bv = *(const bfx8*)(VTs + (dt * 16 + rho) * 464 + (ks * 4 + g) * 16);
                o = __builtin_amdgcn_mfma_f32_16x16x32_bf16(pa, bv, o, 0, 0, 0);
            }
            #pragma unroll
            for (int e = 0; e < 4; ++e) {
                int qrow = q0 + g * 4 + e;
                if (qrow < NTOK)
                    O[obase + (size_t)qrow * 768 + dt * 16 + rho] = (__hip_bfloat16)o[e];
            }
        }
    }
}

// ---------------------------------------------------------------------------
// Head softmax: out[b,:] = softmax(logits[b,:1000] + b_head)
// ---------------------------------------------------------------------------
__global__ __launch_bounds__(256) void shead_k(const float* __restrict__ logits,
                                               const float* __restrict__ bh,
                                               float* __restrict__ out) {
    const int b = blockIdx.x;
    const int t = threadIdx.x;
    __shared__ float lg[1000];
    __shared__ float red[4];

    for (int c = t; c < 1000; c += 256) lg[c] = logits[(size_t)b * 1024 + c] + bh[c];
    __syncthreads();

    float m = -1e30f;
    for (int c = t; c < 1000; c += 256) m = fmaxf(m, lg[c]);
    #pragma unroll
    for (int off = 32; off; off >>= 1) m = fmaxf(m, __shfl_xor(m, off));
    if ((t & 63) == 0) red[t >> 6] = m;
    __syncthreads();
    m = fmaxf(fmaxf(red[0], red[1]), fmaxf(red[2], red[3]));
    __syncthreads();

    float sum = 0.f;
    for (int c = t; c < 1000; c += 256) sum += __expf(lg[c] - m);
    #pragma unroll
    for (int off = 32; off; off >>= 1) sum += __shfl_xor(sum, off);
    if ((t & 63) == 0) red[t >> 6] = sum;
    __syncthreads();
    sum = red[0] + red[1] + red[2] + red[3];
    const float invs = 1.0f / sum;
    for (int c = t; c < 1000; c += 256) out[(size_t)b * 1000 + c] = __expf(lg[c] - m) * invs;
}

// ---------------------------------------------------------------------------
// Driver
// ---------------------------------------------------------------------------
extern "C" void kernel_launch(void* const* d_in, const int* in_sizes, int n_in,
                              void* d_out, int out_size, void* d_ws, size_t ws_size,
                              hipStream_t stream) {
    const float* x        = (const float*)d_in[0];
    const float* ln_p_g   = (const float*)d_in[1];
    const float* ln_p_b   = (const float*)d_in[2];
    const float* W_patch  = (const float*)d_in[3];
    const float* b_patch  = (const float*)d_in[4];
    const float* ln_e_g   = (const float*)d_in[5];
    const float* ln_e_b   = (const float*)d_in[6];
    const float* pos_emb  = (const float*)d_in[7];
    const float* cls_tok  = (const float*)d_in[8];
    const float* ln_a_g   = (const float*)d_in[9];
    const float* ln_a_b   = (const float*)d_in[10];
    const float* Wq       = (const float*)d_in[11];
    const float* Wk       = (const float*)d_in[12];
    const float* Wv       = (const float*)d_in[13];
    const float* Wo       = (const float*)d_in[14];
    const float* bo       = (const float*)d_in[15];
    const float* ln_f_g   = (const float*)d_in[16];
    const float* ln_f_b   = (const float*)d_in[17];
    const float* W1       = (const float*)d_in[18];
    const float* b1       = (const float*)d_in[19];
    const float* W2       = (const float*)d_in[20];
    const float* b2       = (const float*)d_in[21];
    const float* ln_out_g = (const float*)d_in[22];
    const float* ln_out_b = (const float*)d_in[23];
    const float* W_head   = (const float*)d_in[24];
    const float* b_head   = (const float*)d_in[25];

    typedef __hip_bfloat16 bf;
    const int M  = 12608;               // 64*197
    const int MP = 12800;               // padded to 50*256
    char* p = (char*)d_ws;

    float* Z   = (float*)p;            p += (size_t)MP * 768 * 4;      // fp32 residual
    bf* XA     = (bf*)p;               p += (size_t)MP * 768 * 2;      // LN out (bf16)
    bf* QKV    = (bf*)p;               p += (size_t)MP * 2304 * 2;     // fused q,k,v
    bf* OB     = (bf*)p;               p += (size_t)MP * 768 * 2;
    char* FFHc = p;                    p += (size_t)MP * 3072 * 2;     // bf16 GELU buf
    bf* FFH    = (bf*)FFHc;
    float* PE  = (float*)FFHc;                                          // alias: patch-embed fp32
    float* E2  = (float*)(FFHc + (size_t)MP * 768 * 4);                 // alias: ln_e out fp32
    bf* WQKVT  = (bf*)p;               p += (size_t)12 * 2304 * 768 * 2;
    bf* WoT    = (bf*)p;               p += (size_t)12 * 768 * 768 * 2;
    bf* W1T    = (bf*)p;               p += (size_t)12 * 3072 * 768 * 2;
    bf* W2T    = (bf*)p;               p += (size_t)12 * 768 * 3072 * 2;
    bf* WpT    = (bf*)p;               p += (size_t)768 * 768 * 2;
    bf* WhT    = (bf*)p;               p += (size_t)1024 * 768 * 2;
    bf* CLS    = (bf*)p;               p += (size_t)128 * 768 * 2;
    float* LOG = (float*)p;            p += (size_t)64 * 1024 * 4;

    const size_t QKVS = (size_t)2304 * 768;

    // weight convert + transpose (every launch)
    wconv_k<<<dim3(12, 12, 12), 256, 0, stream>>>(Wq, WQKVT,             768, 768,  QKVS);
    wconv_k<<<dim3(12, 12, 12), 256, 0, stream>>>(Wk, WQKVT + 768 * 768, 768, 768,  QKVS);
    wconv_k<<<dim3(12, 12, 12), 256, 0, stream>>>(Wv, WQKVT + 1536 * 768,768, 768,  QKVS);
    wconv_k<<<dim3(12, 12, 12), 256, 0, stream>>>(Wo, WoT,  768, 768,  (size_t)768 * 768);
    wconv_k<<<dim3(48, 12, 12), 256, 0, stream>>>(W1, W1T,  768, 3072, (size_t)3072 * 768);
    wconv_k<<<dim3(12, 48, 12), 256, 0, stream>>>(W2, W2T,  3072, 768, (size_t)768 * 3072);
    wconv_k<<<dim3(12, 12, 1),  256, 0, stream>>>(W_patch, WpT, 768, 768, 0);
    whT_k  <<<dim3(16, 12),     256, 0, stream>>>(W_head, WhT);

    // patch embed pipeline (12544 = 49*256 exactly)
    patch_ln_k<<<12544, 256, 0, stream>>>(x, XA, ln_p_g, ln_p_b);
    mgemm256x128_k<1, float><<<dim3(6, 49), 512, 0, stream>>>(XA, WpT, b_patch, nullptr, PE, 12544, 768, 768);
    ln_k<float><<<12544, 256, 0, stream>>>(PE, E2, ln_e_g, ln_e_b);
    build_z_k<<<37824, 256, 0, stream>>>(E2, cls_tok, pos_emb, Z);

    for (int i = 0; i < 12; ++i) {
        bf* WQKVT_i = WQKVT + (size_t)i * QKVS;
        bf* WoT_i   = WoT + (size_t)i * 768 * 768;
        bf* W1T_i   = W1T + (size_t)i * 3072 * 768;
        bf* W2T_i   = W2T + (size_t)i * 768 * 3072;

        ln_k<bf><<<M, 256, 0, stream>>>(Z, XA, ln_a_g + (size_t)i * 768, ln_a_b + (size_t)i * 768);
        mgemm256x128_k<0, bf><<<dim3(18, 50), 512, 0, stream>>>(XA, WQKVT_i, nullptr, nullptr, QKV, M, 2304, 768);
        attn_k<<<dim3(12, 64), 256, 0, stream>>>(QKV, OB);
        mgemm256x128_k<3, float><<<dim3(6, 50), 512, 0, stream>>>(OB, WoT_i, bo + (size_t)i * 768, Z, Z, M, 768, 768);
        ln_k<bf><<<M, 256, 0, stream>>>(Z, XA, ln_f_g + (size_t)i * 768, ln_f_b + (size_t)i * 768);
        mgemm256x128_k<2, bf><<<dim3(24, 50), 512, 0, stream>>>(XA, W1T_i, b1 + (size_t)i * 3072, nullptr, FFH, M, 3072, 768);
        mgemm256x128_k<3, float><<<dim3(6, 50), 512, 0, stream>>>(FFH, W2T_i, b2 + (size_t)i * 768, Z, Z, M, 768, 3072);
    }

    // head: LN(CLS rows) -> logits GEMM (128^2 kernel) -> softmax
    ln_cls_k<<<128, 256, 0, stream>>>(Z, CLS, ln_out_g, ln_out_b);
    mgemm_k<0, float><<<dim3(8, 1), 256, 0, stream>>>(CLS, WhT, nullptr, nullptr, LOG, 64, 1024, 768);
    shead_k<<<64, 256, 0, stream>>>(LOG, b_head, (float*)d_out);
}

// Round 14
// 4426.193 us; speedup vs baseline: 1.1842x; 1.0395x over previous
//
#include <hip/hip_runtime.h>
#include <hip/hip_bf16.h>
#include <math.h>

#define NTOK 197

typedef __attribute__((ext_vector_type(8))) short bfx8;
typedef __attribute__((ext_vector_type(4))) float fx4;

#define GLOAD16(gsrc, ldst) __builtin_amdgcn_global_load_lds( \
    (const __attribute__((address_space(1))) void*)(gsrc),    \
    (__attribute__((address_space(3))) void*)(ldst), 16, 0, 0)

__device__ __forceinline__ float gelu_f(float x) {
    return 0.5f * x * (1.0f + erff(x * 0.70710678118654752f));
}
__device__ __forceinline__ unsigned short f2bfu(float f) {
    __hip_bfloat16 h = (__hip_bfloat16)f;
    unsigned short u;
    __builtin_memcpy(&u, &h, 2);
    return u;
}

// bijective XCD swizzle (T1, m204): contiguous chunk of blocks per XCD
__device__ __forceinline__ int xcd_swz(int orig, int nwg) {
    const int q8 = nwg >> 3, r8 = nwg & 7;
    const int xcd = orig & 7, idx8 = orig >> 3;
    return (xcd < r8 ? xcd * (q8 + 1) : r8 * (q8 + 1) + (xcd - r8) * q8) + idx8;
}

// ---------------------------------------------------------------------------
// Patch extraction + LayerNorm -> bf16. Coalesced float4 loads staged via LDS.
// ---------------------------------------------------------------------------
__global__ __launch_bounds__(256) void patch_ln_k(const float* __restrict__ x,
                                                  __hip_bfloat16* __restrict__ out,
                                                  const float* __restrict__ g,
                                                  const float* __restrict__ bt) {
    const int r = blockIdx.x;          // 0..12543
    const int t = threadIdx.x;
    const int b = r / 196, p = r % 196;
    const int ph = p / 14, pw = p % 14;

    __shared__ float px[768];
    if (t < 192) {
        int rr = t >> 2, seg = t & 3;
        int c = rr >> 4, h1 = rr & 15;
        const float* src = x + (((size_t)b * 3 + c) * 224 + (ph * 16 + h1)) * 224
                             + pw * 16 + seg * 4;
        float4 v4 = *(const float4*)src;
        px[(h1 * 16 + seg * 4 + 0) * 3 + c] = v4.x;
        px[(h1 * 16 + seg * 4 + 1) * 3 + c] = v4.y;
        px[(h1 * 16 + seg * 4 + 2) * 3 + c] = v4.z;
        px[(h1 * 16 + seg * 4 + 3) * 3 + c] = v4.w;
    }
    __syncthreads();

    float v[3];
    #pragma unroll
    for (int i = 0; i < 3; ++i) v[i] = px[t + i * 256];
    float s = v[0] + v[1] + v[2];
    float sq = v[0]*v[0] + v[1]*v[1] + v[2]*v[2];
    #pragma unroll
    for (int off = 32; off; off >>= 1) { s += __shfl_xor(s, off); sq += __shfl_xor(sq, off); }
    __shared__ float ss[4], s2[4];
    const int w = t >> 6;
    if ((t & 63) == 0) { ss[w] = s; s2[w] = sq; }
    __syncthreads();
    s  = ss[0] + ss[1] + ss[2] + ss[3];
    sq = s2[0] + s2[1] + s2[2] + s2[3];
    const float inv = 1.0f / 768.0f;
    float mu = s * inv;
    float var = sq * inv - mu * mu;
    float rstd = rsqrtf(var + 1e-5f);
    __hip_bfloat16* o = out + (size_t)r * 768;
    #pragma unroll
    for (int i = 0; i < 3; ++i) {
        int d = t + i * 256;
        o[d] = (__hip_bfloat16)((v[i] - mu) * rstd * g[d] + bt[d]);
    }
}

// ---------------------------------------------------------------------------
// Row LayerNorm over 768, wave-per-row (4 rows/block), float4 loads,
// shuffle-only reduce, vector stores. fp32 in -> OT out.
// ---------------------------------------------------------------------------
template <typename OT>
__global__ __launch_bounds__(256) void ln_k(const float* __restrict__ in,
                                            OT* __restrict__ out,
                                            const float* __restrict__ g,
                                            const float* __restrict__ bt,
                                            int nrows) {
    const int w = threadIdx.x >> 6, lane = threadIdx.x & 63;
    const int row = blockIdx.x * 4 + w;
    if (row >= nrows) return;
    const float* xr = in + (size_t)row * 768;

    float4 v[3];
    float s = 0.f, sq = 0.f;
    #pragma unroll
    for (int i = 0; i < 3; ++i) {
        v[i] = *(const float4*)(xr + lane * 4 + i * 256);
        s  += v[i].x + v[i].y + v[i].z + v[i].w;
        sq += v[i].x*v[i].x + v[i].y*v[i].y + v[i].z*v[i].z + v[i].w*v[i].w;
    }
    #pragma unroll
    for (int off = 32; off; off >>= 1) { s += __shfl_xor(s, off); sq += __shfl_xor(sq, off); }
    const float inv = 1.0f / 768.0f;
    float mu = s * inv;
    float rstd = rsqrtf(sq * inv - mu * mu + 1e-5f);

    #pragma unroll
    for (int i = 0; i < 3; ++i) {
        const int col = lane * 4 + i * 256;
        float4 gv = *(const float4*)(g + col);
        float4 bv = *(const float4*)(bt + col);
        float o0 = (v[i].x - mu) * rstd * gv.x + bv.x;
        float o1 = (v[i].y - mu) * rstd * gv.y + bv.y;
        float o2 = (v[i].z - mu) * rstd * gv.z + bv.z;
        float o3 = (v[i].w - mu) * rstd * gv.w + bv.w;
        if constexpr (sizeof(OT) == 2) {
            short4 pk;
            pk.x = (short)f2bfu(o0); pk.y = (short)f2bfu(o1);
            pk.z = (short)f2bfu(o2); pk.w = (short)f2bfu(o3);
            *(short4*)(out + (size_t)row * 768 + col) = pk;
        } else {
            float4 pk = make_float4(o0, o1, o2, o3);
            *(float4*)((float*)out + (size_t)row * 768 + col) = pk;
        }
    }
}

// ---------------------------------------------------------------------------
// LN of CLS rows only -> bf16 [128][768] (rows 64..127 zeroed)
// ---------------------------------------------------------------------------
__global__ __launch_bounds__(256) void ln_cls_k(const float* __restrict__ in,
                                                __hip_bfloat16* __restrict__ out,
                                                const float* __restrict__ g,
                                                const float* __restrict__ bt) {
    const int b = blockIdx.x;   // 0..127
    const int t = threadIdx.x;
    if (b >= 64) {
        #pragma unroll
        for (int i = 0; i < 3; ++i) out[(size_t)b * 768 + t + i * 256] = (__hip_bfloat16)0.0f;
        return;
    }
    const float* xr = in + (size_t)b * 197 * 768;
    float v0 = xr[t], v1 = xr[t + 256], v2 = xr[t + 512];
    float s = v0 + v1 + v2;
    float sq = v0*v0 + v1*v1 + v2*v2;
    #pragma unroll
    for (int off = 32; off; off >>= 1) { s += __shfl_xor(s, off); sq += __shfl_xor(sq, off); }
    __shared__ float ss[4], s2[4];
    const int w = t >> 6;
    if ((t & 63) == 0) { ss[w] = s; s2[w] = sq; }
    __syncthreads();
    s  = ss[0] + ss[1] + ss[2] + ss[3];
    sq = s2[0] + s2[1] + s2[2] + s2[3];
    const float inv = 1.0f / 768.0f;
    float mu = s * inv;
    float var = sq * inv - mu * mu;
    float rstd = rsqrtf(var + 1e-5f);
    __hip_bfloat16* o = out + (size_t)b * 768;
    o[t]       = (__hip_bfloat16)((v0 - mu) * rstd * g[t]       + bt[t]);
    o[t + 256] = (__hip_bfloat16)((v1 - mu) * rstd * g[t + 256] + bt[t + 256]);
    o[t + 512] = (__hip_bfloat16)((v2 - mu) * rstd * g[t + 512] + bt[t + 512]);
}

// ---------------------------------------------------------------------------
// z = concat(cls, p_ln) + pos  -> [64,197,768] fp32
// ---------------------------------------------------------------------------
__global__ __launch_bounds__(256) void build_z_k(const float* __restrict__ pln,
                                                 const float* __restrict__ cls,
                                                 const float* __restrict__ pos,
                                                 float* __restrict__ z) {
    size_t idx = (size_t)blockIdx.x * 256 + threadIdx.x;
    int d  = idx % 768;
    size_t tkb = idx / 768;
    int tk = tkb % 197;
    int b  = tkb / 197;
    float v = (tk == 0) ? cls[d] : pln[((size_t)b * 196 + (tk - 1)) * 768 + d];
    z[idx] = v + pos[(size_t)tk * 768 + d];
}

// ---------------------------------------------------------------------------
// Weight convert + transpose: fp32 [K,N] -> bf16 [N,K], z-strided output.
// float4 global loads; 16B bf16x8 stores (was scalar 2B — write-limited).
// LDS gather is 2-way bank alias only (bank = (8kc+u+nl) mod 32).
// ---------------------------------------------------------------------------
__global__ __launch_bounds__(256) void wconv_k(const float* __restrict__ W,
                                               __hip_bfloat16* __restrict__ Wt,
                                               int K, int N, size_t ostride) {
    __shared__ float tl[64][65];
    const int t = threadIdx.x;
    const int n0 = blockIdx.x * 64, k0 = blockIdx.y * 64;
    const size_t ibase = (size_t)blockIdx.z * K * N;
    const size_t obase = (size_t)blockIdx.z * ostride;
    #pragma unroll
    for (int i = 0; i < 4; ++i) {
        int idx = i * 256 + t;           // 0..1023
        int kl = idx >> 4, nc = idx & 15;
        float4 v4 = *(const float4*)&W[ibase + (size_t)(k0 + kl) * N + n0 + nc * 4];
        tl[kl][nc * 4 + 0] = v4.x;
        tl[kl][nc * 4 + 1] = v4.y;
        tl[kl][nc * 4 + 2] = v4.z;
        tl[kl][nc * 4 + 3] = v4.w;
    }
    __syncthreads();
    #pragma unroll
    for (int i = 0; i < 2; ++i) {
        int idx = i * 256 + t;           // 0..511
        int nl = idx >> 3, kc = idx & 7;
        bfx8 o;
        #pragma unroll
        for (int u = 0; u < 8; ++u) o[u] = (short)f2bfu(tl[kc * 8 + u][nl]);
        *(bfx8*)&Wt[obase + (size_t)(n0 + nl) * K + k0 + kc * 8] = o;
    }
}

// ---------------------------------------------------------------------------
// W_head transpose: fp32 [768][1000] -> bf16 [1024][768], pad rows zeroed
// ---------------------------------------------------------------------------
__global__ __launch_bounds__(256) void whT_k(const float* __restrict__ W,
                                             __hip_bfloat16* __restrict__ Wt) {
    __shared__ float tl[64][65];
    const int t = threadIdx.x;
    const int n0 = blockIdx.x * 64, k0 = blockIdx.y * 64;
    #pragma unroll
    for (int i = 0; i < 16; ++i) {
        int idx = i * 256 + t;
        int kl = idx >> 6, nl = idx & 63;
        int n = n0 + nl;
        tl[kl][nl] = (n < 1000) ? W[(size_t)(k0 + kl) * 1000 + n] : 0.f;
    }
    __syncthreads();
    #pragma unroll
    for (int i = 0; i < 16; ++i) {
        int idx = i * 256 + t;
        int nl = idx >> 6, kl = idx & 63;
        Wt[(size_t)(n0 + nl) * 768 + k0 + kl] = (__hip_bfloat16)tl[kl][nl];
    }
}

// ---------------------------------------------------------------------------
// 128x128 bf16 MFMA GEMM, BK=64 (round-5/10 known-good) + XCD swizzle.
// Used for N=768 GEMMs (Wo, W2, patch) and the head GEMM.
// ---------------------------------------------------------------------------
template <int EPI, typename OT>
__global__ __launch_bounds__(256) void mgemm_k(const __hip_bfloat16* __restrict__ A,
                                               const __hip_bfloat16* __restrict__ Wt,
                                               const float* __restrict__ bias,
                                               const float* __restrict__ resid,
                                               OT* __restrict__ C,
                                               int M, int N, int K) {
    __shared__ __align__(16) char sA[16384];
    __shared__ __align__(16) char sB[16384];
    const int t = threadIdx.x;
    const int lane = t & 63, w = t >> 6;
    const int wr = w >> 1, wc = w & 1;
    const int lrow = lane & 15, lgr = lane >> 4;

    const int gx = gridDim.x;
    const int swz = xcd_swz(blockIdx.y * gx + blockIdx.x, gx * gridDim.y);
    const int bm = (swz / gx) * 128, bn = (swz % gx) * 128;

    const __hip_bfloat16* aSrc[4];
    const __hip_bfloat16* bSrc[4];
    #pragma unroll
    for (int i = 0; i < 4; ++i) {
        int q = t + i * 256;          // 0..1023
        int r = q >> 3, c = q & 7;
        int gc = c ^ (r & 7);
        aSrc[i] = A  + (size_t)(bm + r) * K + gc * 8;
        bSrc[i] = Wt + (size_t)(bn + r) * K + gc * 8;
    }

    int aoff[4][2], boff[4][2];
    #pragma unroll
    for (int m = 0; m < 4; ++m) {
        int ra = wr * 64 + m * 16 + lrow;
        int rb = wc * 64 + m * 16 + lrow;
        #pragma unroll
        for (int ks = 0; ks < 2; ++ks) {
            aoff[m][ks] = ra * 128 + (((ks * 4 + lgr) ^ (ra & 7)) << 4);
            boff[m][ks] = rb * 128 + (((ks * 4 + lgr) ^ (rb & 7)) << 4);
        }
    }

    fx4 acc[4][4];
    #pragma unroll
    for (int m = 0; m < 4; ++m)
        #pragma unroll
        for (int n = 0; n < 4; ++n)
            #pragma unroll
            for (int e = 0; e < 4; ++e) acc[m][n][e] = 0.f;

    for (int k0 = 0; k0 < K; k0 += 64) {
        #pragma unroll
        for (int i = 0; i < 4; ++i) GLOAD16(aSrc[i] + k0, sA + (t + i * 256) * 16);
        #pragma unroll
        for (int i = 0; i < 4; ++i) GLOAD16(bSrc[i] + k0, sB + (t + i * 256) * 16);
        __syncthreads();
        #pragma unroll
        for (int ks = 0; ks < 2; ++ks) {
            bfx8 av[4], bv[4];
            #pragma unroll
            for (int m = 0; m < 4; ++m) {
                av[m] = *(const bfx8*)(sA + aoff[m][ks]);
                bv[m] = *(const bfx8*)(sB + boff[m][ks]);
            }
            #pragma unroll
            for (int m = 0; m < 4; ++m)
                #pragma unroll
                for (int n = 0; n < 4; ++n)
                    acc[m][n] = __builtin_amdgcn_mfma_f32_16x16x32_bf16(av[m], bv[n], acc[m][n], 0, 0, 0);
        }
        __syncthreads();
    }

    #pragma unroll
    for (int m = 0; m < 4; ++m) {
        #pragma unroll
        for (int n = 0; n < 4; ++n) {
            const int col = bn + wc * 64 + n * 16 + lrow;
            float bv2 = (EPI >= 1) ? bias[col] : 0.f;
            #pragma unroll
            for (int e = 0; e < 4; ++e) {
                const int row = bm + wr * 64 + m * 16 + lgr * 4 + e;
                if (row < M) {
                    float v = acc[m][n][e] + bv2;
                    if (EPI == 2) v = gelu_f(v);
                    if (EPI == 3) v += resid[(size_t)row * N + col];
                    C[(size_t)row * N + col] = (OT)v;
                }
            }
        }
    }
}

// ---------------------------------------------------------------------------
// 256x128 bf16 MFMA GEMM, BK=64 — the round-10 proven workhorse.
// 512 thr / 8 waves (4 row x 2 col), 48 KB LDS -> 3 blocks/CU.
// __launch_bounds__(512, 4): VGPR cap 128 (no spill; R9's (512,6) spilled).
// Used for QKV (18x50) and FF1 (24x50) where the grid stays >=900 blocks.
// N%128==0, K%64==0, A needs ceil(M/256)*256 readable rows.
// ---------------------------------------------------------------------------
template <int EPI, typename OT>
__global__ __launch_bounds__(512, 4) void mgemm256x128_k(const __hip_bfloat16* __restrict__ A,
                                                         const __hip_bfloat16* __restrict__ Wt,
                                                         const float* __restrict__ bias,
                                                         const float* __restrict__ resid,
                                                         OT* __restrict__ C,
                                                         int M, int N, int K) {
    __shared__ __align__(16) char sA[32768];   // 256 rows x 128B
    __shared__ __align__(16) char sB[16384];   // 128 rows x 128B
    const int t = threadIdx.x;            // 0..511
    const int lane = t & 63, w = t >> 6;  // 8 waves
    const int wr = w >> 1, wc = w & 1;    // 4 x 2 -> 64 x 64 per wave
    const int lrow = lane & 15, lgr = lane >> 4;

    const int gx = gridDim.x;
    const int swz = xcd_swz(blockIdx.y * gx + blockIdx.x, gx * gridDim.y);
    const int bm = (swz / gx) * 256, bn = (swz % gx) * 128;

    const __hip_bfloat16* aSrc[4];
    const __hip_bfloat16* bSrc[2];
    #pragma unroll
    for (int i = 0; i < 4; ++i) {
        int q = t + i * 512;              // 0..2047 -> 256 rows x 8 chunks
        int r = q >> 3, c = q & 7;
        int gc = c ^ (r & 7);
        aSrc[i] = A + (size_t)(bm + r) * K + gc * 8;
    }
    #pragma unroll
    for (int i = 0; i < 2; ++i) {
        int q = t + i * 512;              // 0..1023 -> 128 rows x 8 chunks
        int r = q >> 3, c = q & 7;
        int gc = c ^ (r & 7);
        bSrc[i] = Wt + (size_t)(bn + r) * K + gc * 8;
    }

    int aoff[4][2], boff[4][2];
    #pragma unroll
    for (int m = 0; m < 4; ++m) {
        int ra = wr * 64 + m * 16 + lrow;
        int rb = wc * 64 + m * 16 + lrow;
        #pragma unroll
        for (int ks = 0; ks < 2; ++ks) {
            aoff[m][ks] = ra * 128 + (((ks * 4 + lgr) ^ (ra & 7)) << 4);
            boff[m][ks] = rb * 128 + (((ks * 4 + lgr) ^ (rb & 7)) << 4);
        }
    }

    fx4 acc[4][4];
    #pragma unroll
    for (int m = 0; m < 4; ++m)
        #pragma unroll
        for (int n = 0; n < 4; ++n)
            #pragma unroll
            for (int e = 0; e < 4; ++e) acc[m][n][e] = 0.f;

    for (int k0 = 0; k0 < K; k0 += 64) {
        #pragma unroll
        for (int i = 0; i < 4; ++i) GLOAD16(aSrc[i] + k0, sA + (t + i * 512) * 16);
        #pragma unroll
        for (int i = 0; i < 2; ++i) GLOAD16(bSrc[i] + k0, sB + (t + i * 512) * 16);
        __syncthreads();
        #pragma unroll
        for (int ks = 0; ks < 2; ++ks) {
            bfx8 av[4], bv[4];
            #pragma unroll
            for (int m = 0; m < 4; ++m) {
                av[m] = *(const bfx8*)(sA + aoff[m][ks]);
                bv[m] = *(const bfx8*)(sB + boff[m][ks]);
            }
            #pragma unroll
            for (int m = 0; m < 4; ++m)
                #pragma unroll
                for (int n = 0; n < 4; ++n)
                    acc[m][n] = __builtin_amdgcn_mfma_f32_16x16x32_bf16(av[m], bv[n], acc[m][n], 0, 0, 0);
        }
        __syncthreads();
    }

    #pragma unroll
    for (int m = 0; m < 4; ++m) {
        #pragma unroll
        for (int n = 0; n < 4; ++n) {
            const int col = bn + wc * 64 + n * 16 + lrow;
            float bv2 = (EPI >= 1) ? bias[col] : 0.f;
            #pragma unroll
            for (int e = 0; e < 4; ++e) {
                const int row = bm + wr * 64 + m * 16 + lgr * 4 + e;
                if (row < M) {
                    float v = acc[m][n][e] + bv2;
                    if (EPI == 2) v = gelu_f(v);
                    if (EPI == 3) v += resid[(size_t)row * N + col];
                    C[(size_t)row * N + col] = (OT)v;
                }
            }
        }
    }
}

// ---------------------------------------------------------------------------
// MFMA fused attention on fused QKV buffer (row stride 2304).
// ---------------------------------------------------------------------------
__global__ __launch_bounds__(256) void attn_k(const __hip_bfloat16* __restrict__ QKV,
                                              __hip_bfloat16* __restrict__ O) {
    __shared__ __align__(16) char Ks[224 * 128];   // 28672
    __shared__ __align__(16) char VTs[64 * 464];   // 29696
    __shared__ __align__(16) char Ps[4][7424];     // 4 x (16 rows x 464B)

    const int h = blockIdx.x;
    const int b = blockIdx.y;
    const int t = threadIdx.x;
    const int lane = t & 63, w = t >> 6;
    const int rho = lane & 15, g = lane >> 4;
    const size_t base = (size_t)b * NTOK * 2304;
    const int qoff = h * 64, koff = 768 + h * 64, voff = 1536 + h * 64;
    const size_t obase = ((size_t)b * NTOK) * 768 + h * 64;

    #pragma unroll
    for (int i = 0; i < 7; ++i) {
        int q = t + i * 256;            // 0..1791
        int j = q >> 3, c = q & 7;
        int gc = c ^ (j & 7);
        GLOAD16(QKV + base + (size_t)j * 2304 + koff + gc * 8, Ks + q * 16);
    }
    #pragma unroll
    for (int i = 0; i < 7; ++i) {
        int q = t + i * 256;
        int tok = q >> 3, c = q & 7;
        bfx8 vv = {0, 0, 0, 0, 0, 0, 0, 0};
        if (tok < NTOK) vv = *(const bfx8*)(QKV + base + (size_t)tok * 2304 + voff + c * 8);
        #pragma unroll
        for (int u = 0; u < 8; ++u)
            *(unsigned short*)(VTs + (c * 8 + u) * 464 + tok * 2) = (unsigned short)vv[u];
    }
    __syncthreads();

    char* Pw = Ps[w];

    for (int qt = w; qt < 13; qt += 4) {
        const int q0 = qt * 16;
        fx4 s[13];
        #pragma unroll
        for (int nt = 0; nt < 13; ++nt)
            #pragma unroll
            for (int e = 0; e < 4; ++e) s[nt][e] = 0.f;
        #pragma unroll
        for (int ks = 0; ks < 2; ++ks) {
            bfx8 av = *(const bfx8*)(QKV + base + (size_t)(q0 + rho) * 2304 + qoff + ks * 32 + g * 8);
            #pragma unroll
            for (int nt = 0; nt < 13; ++nt) {
                int r = nt * 16 + rho;
                bfx8 bv = *(const bfx8*)(Ks + r * 128 + (((ks * 4 + g) ^ (r & 7)) << 4));
                s[nt] = __builtin_amdgcn_mfma_f32_16x16x32_bf16(av, bv, s[nt], 0, 0, 0);
            }
        }
        float mx[4] = {-1e30f, -1e30f, -1e30f, -1e30f};
        #pragma unroll
        for (int nt = 0; nt < 13; ++nt) {
            #pragma unroll
            for (int e = 0; e < 4; ++e) {
                float v = s[nt][e] * 0.125f;
                if (nt == 12 && rho >= 5) v = -1e30f;
                s[nt][e] = v;
                mx[e] = fmaxf(mx[e], v);
            }
        }
        #pragma unroll
        for (int off = 1; off < 16; off <<= 1)
            #pragma unroll
            for (int e = 0; e < 4; ++e) mx[e] = fmaxf(mx[e], __shfl_xor(mx[e], off));
        float sm[4] = {0.f, 0.f, 0.f, 0.f};
        #pragma unroll
        for (int nt = 0; nt < 13; ++nt)
            #pragma unroll
            for (int e = 0; e < 4; ++e) {
                float p = __expf(s[nt][e] - mx[e]);
                s[nt][e] = p;
                sm[e] += p;
            }
        #pragma unroll
        for (int off = 1; off < 16; off <<= 1)
            #pragma unroll
            for (int e = 0; e < 4; ++e) sm[e] += __shfl_xor(sm[e], off);
        float inv[4];
        #pragma unroll
        for (int e = 0; e < 4; ++e) inv[e] = 1.0f / sm[e];

        #pragma unroll
        for (int nt = 0; nt < 13; ++nt)
            #pragma unroll
            for (int e = 0; e < 4; ++e) {
                int row = g * 4 + e;
                int col = nt * 16 + rho;
                *(__hip_bfloat16*)(Pw + row * 464 + col * 2) =
                    (__hip_bfloat16)(s[nt][e] * inv[e]);
            }
        #pragma unroll
        for (int e = 0; e < 4; ++e)
            *(__hip_bfloat16*)(Pw + (g * 4 + e) * 464 + (208 + rho) * 2) = (__hip_bfloat16)0.0f;

        __builtin_amdgcn_sched_barrier(0);
        asm volatile("s_waitcnt lgkmcnt(0)" ::: "memory");
        __builtin_amdgcn_sched_barrier(0);

        #pragma unroll
        for (int dt = 0; dt < 4; ++dt) {
            fx4 o;
            #pragma unroll
            for (int e = 0; e < 4; ++e) o[e] = 0.f;
            #pragma unroll
            for (int ks = 0; ks < 7; ++ks) {
                bfx8 pa = *(const bfx8*)(Pw + rho * 464 + (ks * 4 + g) * 16);
                bfx8 bv = *(const bfx8*)(VTs + (dt * 16 + rho) * 464 + (ks * 4 + g) * 16);
                o = __builtin_amdgcn_mfma_f32_16x16x32_bf16(pa, bv, o, 0, 0, 0);
            }
            #pragma unroll
            for (int e = 0; e < 4; ++e) {
                int qrow = q0 + g * 4 + e;
                if (qrow < NTOK)
                    O[obase + (size_t)qrow * 768 + dt * 16 + rho] = (__hip_bfloat16)o[e];
            }
        }
    }
}

// ---------------------------------------------------------------------------
// Head softmax: out[b,:] = softmax(logits[b,:1000] + b_head)
// ---------------------------------------------------------------------------
__global__ __launch_bounds__(256) void shead_k(const float* __restrict__ logits,
                                               const float* __restrict__ bh,
                                               float* __restrict__ out) {
    const int b = blockIdx.x;
    const int t = threadIdx.x;
    __shared__ float lg[1000];
    __shared__ float red[4];

    for (int c = t; c < 1000; c += 256) lg[c] = logits[(size_t)b * 1024 + c] + bh[c];
    __syncthreads();

    float m = -1e30f;
    for (int c = t; c < 1000; c += 256) m = fmaxf(m, lg[c]);
    #pragma unroll
    for (int off = 32; off; off >>= 1) m = fmaxf(m, __shfl_xor(m, off));
    if ((t & 63) == 0) red[t >> 6] = m;
    __syncthreads();
    m = fmaxf(fmaxf(red[0], red[1]), fmaxf(red[2], red[3]));
    __syncthreads();

    float sum = 0.f;
    for (int c = t; c < 1000; c += 256) sum += __expf(lg[c] - m);
    #pragma unroll
    for (int off = 32; off; off >>= 1) sum += __shfl_xor(sum, off);
    if ((t & 63) == 0) red[t >> 6] = sum;
    __syncthreads();
    sum = red[0] + red[1] + red[2] + red[3];
    const float invs = 1.0f / sum;
    for (int c = t; c < 1000; c += 256) out[(size_t)b * 1000 + c] = __expf(lg[c] - m) * invs;
}

// ---------------------------------------------------------------------------
// Driver
// ---------------------------------------------------------------------------
extern "C" void kernel_launch(void* const* d_in, const int* in_sizes, int n_in,
                              void* d_out, int out_size, void* d_ws, size_t ws_size,
                              hipStream_t stream) {
    const float* x        = (const float*)d_in[0];
    const float* ln_p_g   = (const float*)d_in[1];
    const float* ln_p_b   = (const float*)d_in[2];
    const float* W_patch  = (const float*)d_in[3];
    const float* b_patch  = (const float*)d_in[4];
    const float* ln_e_g   = (const float*)d_in[5];
    const float* ln_e_b   = (const float*)d_in[6];
    const float* pos_emb  = (const float*)d_in[7];
    const float* cls_tok  = (const float*)d_in[8];
    const float* ln_a_g   = (const float*)d_in[9];
    const float* ln_a_b   = (const float*)d_in[10];
    const float* Wq       = (const float*)d_in[11];
    const float* Wk       = (const float*)d_in[12];
    const float* Wv       = (const float*)d_in[13];
    const float* Wo       = (const float*)d_in[14];
    const float* bo       = (const float*)d_in[15];
    const float* ln_f_g   = (const float*)d_in[16];
    const float* ln_f_b   = (const float*)d_in[17];
    const float* W1       = (const float*)d_in[18];
    const float* b1       = (const float*)d_in[19];
    const float* W2       = (const float*)d_in[20];
    const float* b2       = (const float*)d_in[21];
    const float* ln_out_g = (const float*)d_in[22];
    const float* ln_out_b = (const float*)d_in[23];
    const float* W_head   = (const float*)d_in[24];
    const float* b_head   = (const float*)d_in[25];

    typedef __hip_bfloat16 bf;
    const int M  = 12608;               // 64*197
    const int MP = 12800;               // padded to 50*256
    char* p = (char*)d_ws;

    float* Z   = (float*)p;            p += (size_t)MP * 768 * 4;      // fp32 residual
    bf* XA     = (bf*)p;               p += (size_t)MP * 768 * 2;      // LN out (bf16)
    bf* QKV    = (bf*)p;               p += (size_t)MP * 2304 * 2;     // fused q,k,v
    bf* OB     = (bf*)p;               p += (size_t)MP * 768 * 2;
    char* FFHc = p;                    p += (size_t)MP * 3072 * 2;     // bf16 GELU buf
    bf* FFH    = (bf*)FFHc;
    float* PE  = (float*)FFHc;                                          // alias: patch-embed fp32
    float* E2  = (float*)(FFHc + (size_t)MP * 768 * 4);                 // alias: ln_e out fp32
    bf* WQKVT  = (bf*)p;               p += (size_t)12 * 2304 * 768 * 2;
    bf* WoT    = (bf*)p;               p += (size_t)12 * 768 * 768 * 2;
    bf* W1T    = (bf*)p;               p += (size_t)12 * 3072 * 768 * 2;
    bf* W2T    = (bf*)p;               p += (size_t)12 * 768 * 3072 * 2;
    bf* WpT    = (bf*)p;               p += (size_t)768 * 768 * 2;
    bf* WhT    = (bf*)p;               p += (size_t)1024 * 768 * 2;
    bf* CLS    = (bf*)p;               p += (size_t)128 * 768 * 2;
    float* LOG = (float*)p;            p += (size_t)64 * 1024 * 4;

    const size_t QKVS = (size_t)2304 * 768;

    // weight convert + transpose (every launch)
    wconv_k<<<dim3(12, 12, 12), 256, 0, stream>>>(Wq, WQKVT,             768, 768,  QKVS);
    wconv_k<<<dim3(12, 12, 12), 256, 0, stream>>>(Wk, WQKVT + 768 * 768, 768, 768,  QKVS);
    wconv_k<<<dim3(12, 12, 12), 256, 0, stream>>>(Wv, WQKVT + 1536 * 768,768, 768,  QKVS);
    wconv_k<<<dim3(12, 12, 12), 256, 0, stream>>>(Wo, WoT,  768, 768,  (size_t)768 * 768);
    wconv_k<<<dim3(48, 12, 12), 256, 0, stream>>>(W1, W1T,  768, 3072, (size_t)3072 * 768);
    wconv_k<<<dim3(12, 48, 12), 256, 0, stream>>>(W2, W2T,  3072, 768, (size_t)768 * 3072);
    wconv_k<<<dim3(12, 12, 1),  256, 0, stream>>>(W_patch, WpT, 768, 768, 0);
    whT_k  <<<dim3(16, 12),     256, 0, stream>>>(W_head, WhT);

    // patch embed pipeline
    patch_ln_k<<<12544, 256, 0, stream>>>(x, XA, ln_p_g, ln_p_b);
    mgemm_k<1, float><<<dim3(6, 98), 256, 0, stream>>>(XA, WpT, b_patch, nullptr, PE, 12544, 768, 768);
    ln_k<float><<<3136, 256, 0, stream>>>(PE, E2, ln_e_g, ln_e_b, 12544);
    build_z_k<<<37824, 256, 0, stream>>>(E2, cls_tok, pos_emb, Z);

    for (int i = 0; i < 12; ++i) {
        bf* WQKVT_i = WQKVT + (size_t)i * QKVS;
        bf* WoT_i   = WoT + (size_t)i * 768 * 768;
        bf* W1T_i   = W1T + (size_t)i * 3072 * 768;
        bf* W2T_i   = W2T + (size_t)i * 768 * 3072;

        ln_k<bf><<<3152, 256, 0, stream>>>(Z, XA, ln_a_g + (size_t)i * 768, ln_a_b + (size_t)i * 768, M);
        mgemm256x128_k<0, bf><<<dim3(18, 50), 512, 0, stream>>>(XA, WQKVT_i, nullptr, nullptr, QKV, M, 2304, 768);
        attn_k<<<dim3(12, 64), 256, 0, stream>>>(QKV, OB);
        mgemm_k<3, float><<<dim3(6, 99), 256, 0, stream>>>(OB, WoT_i, bo + (size_t)i * 768, Z, Z, M, 768, 768);
        ln_k<bf><<<3152, 256, 0, stream>>>(Z, XA, ln_f_g + (size_t)i * 768, ln_f_b + (size_t)i * 768, M);
        mgemm256x128_k<2, bf><<<dim3(24, 50), 512, 0, stream>>>(XA, W1T_i, b1 + (size_t)i * 3072, nullptr, FFH, M, 3072, 768);
        mgemm_k<3, float><<<dim3(6, 99), 256, 0, stream>>>(FFH, W2T_i, b2 + (size_t)i * 768, Z, Z, M, 768, 3072);
    }

    // head: LN(CLS rows) -> logits GEMM (128^2 kernel) -> softmax
    ln_cls_k<<<128, 256, 0, stream>>>(Z, CLS, ln_out_g, ln_out_b);
    mgemm_k<0, float><<<dim3(8, 1), 256, 0, stream>>>(CLS, WhT, nullptr, nullptr, LOG, 64, 1024, 768);
    shead_k<<<64, 256, 0, stream>>>(LOG, b_head, (float*)d_out);
}

// Round 15
// 4245.829 us; speedup vs baseline: 1.2345x; 1.0425x over previous
//
#include <hip/hip_runtime.h>
#include <hip/hip_bf16.h>
#include <math.h>

#define NTOK 197

typedef __attribute__((ext_vector_type(8))) short bfx8;
typedef __attribute__((ext_vector_type(4))) float fx4;

#define GLOAD16(gsrc, ldst) __builtin_amdgcn_global_load_lds( \
    (const __attribute__((address_space(1))) void*)(gsrc),    \
    (__attribute__((address_space(3))) void*)(ldst), 16, 0, 0)

__device__ __forceinline__ float gelu_f(float x) {
    return 0.5f * x * (1.0f + erff(x * 0.70710678118654752f));
}
__device__ __forceinline__ unsigned short f2bfu(float f) {
    __hip_bfloat16 h = (__hip_bfloat16)f;
    unsigned short u;
    __builtin_memcpy(&u, &h, 2);
    return u;
}

// bijective XCD swizzle (T1, m204): contiguous chunk of blocks per XCD
__device__ __forceinline__ int xcd_swz(int orig, int nwg) {
    const int q8 = nwg >> 3, r8 = nwg & 7;
    const int xcd = orig & 7, idx8 = orig >> 3;
    return (xcd < r8 ? xcd * (q8 + 1) : r8 * (q8 + 1) + (xcd - r8) * q8) + idx8;
}

// ---------------------------------------------------------------------------
// Patch extraction + LayerNorm -> bf16. Coalesced float4 loads staged via LDS.
// ---------------------------------------------------------------------------
__global__ __launch_bounds__(256) void patch_ln_k(const float* __restrict__ x,
                                                  __hip_bfloat16* __restrict__ out,
                                                  const float* __restrict__ g,
                                                  const float* __restrict__ bt) {
    const int r = blockIdx.x;          // 0..12543
    const int t = threadIdx.x;
    const int b = r / 196, p = r % 196;
    const int ph = p / 14, pw = p % 14;

    __shared__ float px[768];
    if (t < 192) {
        int rr = t >> 2, seg = t & 3;
        int c = rr >> 4, h1 = rr & 15;
        const float* src = x + (((size_t)b * 3 + c) * 224 + (ph * 16 + h1)) * 224
                             + pw * 16 + seg * 4;
        float4 v4 = *(const float4*)src;
        px[(h1 * 16 + seg * 4 + 0) * 3 + c] = v4.x;
        px[(h1 * 16 + seg * 4 + 1) * 3 + c] = v4.y;
        px[(h1 * 16 + seg * 4 + 2) * 3 + c] = v4.z;
        px[(h1 * 16 + seg * 4 + 3) * 3 + c] = v4.w;
    }
    __syncthreads();

    float v[3];
    #pragma unroll
    for (int i = 0; i < 3; ++i) v[i] = px[t + i * 256];
    float s = v[0] + v[1] + v[2];
    float sq = v[0]*v[0] + v[1]*v[1] + v[2]*v[2];
    #pragma unroll
    for (int off = 32; off; off >>= 1) { s += __shfl_xor(s, off); sq += __shfl_xor(sq, off); }
    __shared__ float ss[4], s2[4];
    const int w = t >> 6;
    if ((t & 63) == 0) { ss[w] = s; s2[w] = sq; }
    __syncthreads();
    s  = ss[0] + ss[1] + ss[2] + ss[3];
    sq = s2[0] + s2[1] + s2[2] + s2[3];
    const float inv = 1.0f / 768.0f;
    float mu = s * inv;
    float var = sq * inv - mu * mu;
    float rstd = rsqrtf(var + 1e-5f);
    __hip_bfloat16* o = out + (size_t)r * 768;
    #pragma unroll
    for (int i = 0; i < 3; ++i) {
        int d = t + i * 256;
        o[d] = (__hip_bfloat16)((v[i] - mu) * rstd * g[d] + bt[d]);
    }
}

// ---------------------------------------------------------------------------
// Row LayerNorm over 768, wave-per-row (4 rows/block), float4 loads,
// shuffle-only reduce, vector stores. fp32 in -> OT out.
// ---------------------------------------------------------------------------
template <typename OT>
__global__ __launch_bounds__(256) void ln_k(const float* __restrict__ in,
                                            OT* __restrict__ out,
                                            const float* __restrict__ g,
                                            const float* __restrict__ bt,
                                            int nrows) {
    const int w = threadIdx.x >> 6, lane = threadIdx.x & 63;
    const int row = blockIdx.x * 4 + w;
    if (row >= nrows) return;
    const float* xr = in + (size_t)row * 768;

    float4 v[3];
    float s = 0.f, sq = 0.f;
    #pragma unroll
    for (int i = 0; i < 3; ++i) {
        v[i] = *(const float4*)(xr + lane * 4 + i * 256);
        s  += v[i].x + v[i].y + v[i].z + v[i].w;
        sq += v[i].x*v[i].x + v[i].y*v[i].y + v[i].z*v[i].z + v[i].w*v[i].w;
    }
    #pragma unroll
    for (int off = 32; off; off >>= 1) { s += __shfl_xor(s, off); sq += __shfl_xor(sq, off); }
    const float inv = 1.0f / 768.0f;
    float mu = s * inv;
    float rstd = rsqrtf(sq * inv - mu * mu + 1e-5f);

    #pragma unroll
    for (int i = 0; i < 3; ++i) {
        const int col = lane * 4 + i * 256;
        float4 gv = *(const float4*)(g + col);
        float4 bv = *(const float4*)(bt + col);
        float o0 = (v[i].x - mu) * rstd * gv.x + bv.x;
        float o1 = (v[i].y - mu) * rstd * gv.y + bv.y;
        float o2 = (v[i].z - mu) * rstd * gv.z + bv.z;
        float o3 = (v[i].w - mu) * rstd * gv.w + bv.w;
        if constexpr (sizeof(OT) == 2) {
            short4 pk;
            pk.x = (short)f2bfu(o0); pk.y = (short)f2bfu(o1);
            pk.z = (short)f2bfu(o2); pk.w = (short)f2bfu(o3);
            *(short4*)(out + (size_t)row * 768 + col) = pk;
        } else {
            float4 pk = make_float4(o0, o1, o2, o3);
            *(float4*)((float*)out + (size_t)row * 768 + col) = pk;
        }
    }
}

// ---------------------------------------------------------------------------
// LN of CLS rows only -> bf16 [128][768] (rows 64..127 zeroed)
// ---------------------------------------------------------------------------
__global__ __launch_bounds__(256) void ln_cls_k(const float* __restrict__ in,
                                                __hip_bfloat16* __restrict__ out,
                                                const float* __restrict__ g,
                                                const float* __restrict__ bt) {
    const int b = blockIdx.x;   // 0..127
    const int t = threadIdx.x;
    if (b >= 64) {
        #pragma unroll
        for (int i = 0; i < 3; ++i) out[(size_t)b * 768 + t + i * 256] = (__hip_bfloat16)0.0f;
        return;
    }
    const float* xr = in + (size_t)b * 197 * 768;
    float v0 = xr[t], v1 = xr[t + 256], v2 = xr[t + 512];
    float s = v0 + v1 + v2;
    float sq = v0*v0 + v1*v1 + v2*v2;
    #pragma unroll
    for (int off = 32; off; off >>= 1) { s += __shfl_xor(s, off); sq += __shfl_xor(sq, off); }
    __shared__ float ss[4], s2[4];
    const int w = t >> 6;
    if ((t & 63) == 0) { ss[w] = s; s2[w] = sq; }
    __syncthreads();
    s  = ss[0] + ss[1] + ss[2] + ss[3];
    sq = s2[0] + s2[1] + s2[2] + s2[3];
    const float inv = 1.0f / 768.0f;
    float mu = s * inv;
    float var = sq * inv - mu * mu;
    float rstd = rsqrtf(var + 1e-5f);
    __hip_bfloat16* o = out + (size_t)b * 768;
    o[t]       = (__hip_bfloat16)((v0 - mu) * rstd * g[t]       + bt[t]);
    o[t + 256] = (__hip_bfloat16)((v1 - mu) * rstd * g[t + 256] + bt[t + 256]);
    o[t + 512] = (__hip_bfloat16)((v2 - mu) * rstd * g[t + 512] + bt[t + 512]);
}

// ---------------------------------------------------------------------------
// z = concat(cls, p_ln) + pos  -> [64,197,768] fp32
// ---------------------------------------------------------------------------
__global__ __launch_bounds__(256) void build_z_k(const float* __restrict__ pln,
                                                 const float* __restrict__ cls,
                                                 const float* __restrict__ pos,
                                                 float* __restrict__ z) {
    size_t idx = (size_t)blockIdx.x * 256 + threadIdx.x;
    int d  = idx % 768;
    size_t tkb = idx / 768;
    int tk = tkb % 197;
    int b  = tkb / 197;
    float v = (tk == 0) ? cls[d] : pln[((size_t)b * 196 + (tk - 1)) * 768 + d];
    z[idx] = v + pos[(size_t)tk * 768 + d];
}

// ---------------------------------------------------------------------------
// Weight convert + transpose: fp32 [K,N] -> bf16 [N,K], z-strided output.
// float4 global loads; 16B bf16x8 stores. LDS gather 2-way alias only.
// ---------------------------------------------------------------------------
__global__ __launch_bounds__(256) void wconv_k(const float* __restrict__ W,
                                               __hip_bfloat16* __restrict__ Wt,
                                               int K, int N, size_t ostride) {
    __shared__ float tl[64][65];
    const int t = threadIdx.x;
    const int n0 = blockIdx.x * 64, k0 = blockIdx.y * 64;
    const size_t ibase = (size_t)blockIdx.z * K * N;
    const size_t obase = (size_t)blockIdx.z * ostride;
    #pragma unroll
    for (int i = 0; i < 4; ++i) {
        int idx = i * 256 + t;           // 0..1023
        int kl = idx >> 4, nc = idx & 15;
        float4 v4 = *(const float4*)&W[ibase + (size_t)(k0 + kl) * N + n0 + nc * 4];
        tl[kl][nc * 4 + 0] = v4.x;
        tl[kl][nc * 4 + 1] = v4.y;
        tl[kl][nc * 4 + 2] = v4.z;
        tl[kl][nc * 4 + 3] = v4.w;
    }
    __syncthreads();
    #pragma unroll
    for (int i = 0; i < 2; ++i) {
        int idx = i * 256 + t;           // 0..511
        int nl = idx >> 3, kc = idx & 7;
        bfx8 o;
        #pragma unroll
        for (int u = 0; u < 8; ++u) o[u] = (short)f2bfu(tl[kc * 8 + u][nl]);
        *(bfx8*)&Wt[obase + (size_t)(n0 + nl) * K + k0 + kc * 8] = o;
    }
}

// ---------------------------------------------------------------------------
// W_head transpose: fp32 [768][1000] -> bf16 [1024][768], pad rows zeroed
// ---------------------------------------------------------------------------
__global__ __launch_bounds__(256) void whT_k(const float* __restrict__ W,
                                             __hip_bfloat16* __restrict__ Wt) {
    __shared__ float tl[64][65];
    const int t = threadIdx.x;
    const int n0 = blockIdx.x * 64, k0 = blockIdx.y * 64;
    #pragma unroll
    for (int i = 0; i < 16; ++i) {
        int idx = i * 256 + t;
        int kl = idx >> 6, nl = idx & 63;
        int n = n0 + nl;
        tl[kl][nl] = (n < 1000) ? W[(size_t)(k0 + kl) * 1000 + n] : 0.f;
    }
    __syncthreads();
    #pragma unroll
    for (int i = 0; i < 16; ++i) {
        int idx = i * 256 + t;
        int nl = idx >> 6, kl = idx & 63;
        Wt[(size_t)(n0 + nl) * 768 + k0 + kl] = (__hip_bfloat16)tl[kl][nl];
    }
}

// ---------------------------------------------------------------------------
// 128x128 bf16 MFMA GEMM, BK=64 (round-5/10 known-good) + XCD swizzle.
// Used for N=768 GEMMs (Wo, W2, patch) and the head GEMM.
// ---------------------------------------------------------------------------
template <int EPI, typename OT>
__global__ __launch_bounds__(256) void mgemm_k(const __hip_bfloat16* __restrict__ A,
                                               const __hip_bfloat16* __restrict__ Wt,
                                               const float* __restrict__ bias,
                                               const float* __restrict__ resid,
                                               OT* __restrict__ C,
                                               int M, int N, int K) {
    __shared__ __align__(16) char sA[16384];
    __shared__ __align__(16) char sB[16384];
    const int t = threadIdx.x;
    const int lane = t & 63, w = t >> 6;
    const int wr = w >> 1, wc = w & 1;
    const int lrow = lane & 15, lgr = lane >> 4;

    const int gx = gridDim.x;
    const int swz = xcd_swz(blockIdx.y * gx + blockIdx.x, gx * gridDim.y);
    const int bm = (swz / gx) * 128, bn = (swz % gx) * 128;

    const __hip_bfloat16* aSrc[4];
    const __hip_bfloat16* bSrc[4];
    #pragma unroll
    for (int i = 0; i < 4; ++i) {
        int q = t + i * 256;          // 0..1023
        int r = q >> 3, c = q & 7;
        int gc = c ^ (r & 7);
        aSrc[i] = A  + (size_t)(bm + r) * K + gc * 8;
        bSrc[i] = Wt + (size_t)(bn + r) * K + gc * 8;
    }

    int aoff[4][2], boff[4][2];
    #pragma unroll
    for (int m = 0; m < 4; ++m) {
        int ra = wr * 64 + m * 16 + lrow;
        int rb = wc * 64 + m * 16 + lrow;
        #pragma unroll
        for (int ks = 0; ks < 2; ++ks) {
            aoff[m][ks] = ra * 128 + (((ks * 4 + lgr) ^ (ra & 7)) << 4);
            boff[m][ks] = rb * 128 + (((ks * 4 + lgr) ^ (rb & 7)) << 4);
        }
    }

    fx4 acc[4][4];
    #pragma unroll
    for (int m = 0; m < 4; ++m)
        #pragma unroll
        for (int n = 0; n < 4; ++n)
            #pragma unroll
            for (int e = 0; e < 4; ++e) acc[m][n][e] = 0.f;

    for (int k0 = 0; k0 < K; k0 += 64) {
        #pragma unroll
        for (int i = 0; i < 4; ++i) GLOAD16(aSrc[i] + k0, sA + (t + i * 256) * 16);
        #pragma unroll
        for (int i = 0; i < 4; ++i) GLOAD16(bSrc[i] + k0, sB + (t + i * 256) * 16);
        __syncthreads();
        #pragma unroll
        for (int ks = 0; ks < 2; ++ks) {
            bfx8 av[4], bv[4];
            #pragma unroll
            for (int m = 0; m < 4; ++m) {
                av[m] = *(const bfx8*)(sA + aoff[m][ks]);
                bv[m] = *(const bfx8*)(sB + boff[m][ks]);
            }
            #pragma unroll
            for (int m = 0; m < 4; ++m)
                #pragma unroll
                for (int n = 0; n < 4; ++n)
                    acc[m][n] = __builtin_amdgcn_mfma_f32_16x16x32_bf16(av[m], bv[n], acc[m][n], 0, 0, 0);
        }
        __syncthreads();
    }

    #pragma unroll
    for (int m = 0; m < 4; ++m) {
        #pragma unroll
        for (int n = 0; n < 4; ++n) {
            const int col = bn + wc * 64 + n * 16 + lrow;
            float bv2 = (EPI >= 1) ? bias[col] : 0.f;
            #pragma unroll
            for (int e = 0; e < 4; ++e) {
                const int row = bm + wr * 64 + m * 16 + lgr * 4 + e;
                if (row < M) {
                    float v = acc[m][n][e] + bv2;
                    if (EPI == 2) v = gelu_f(v);
                    if (EPI == 3) v += resid[(size_t)row * N + col];
                    C[(size_t)row * N + col] = (OT)v;
                }
            }
        }
    }
}

// ---------------------------------------------------------------------------
// 256x128 bf16 MFMA GEMM, BK=64 — the round-10 proven workhorse.
// 512 thr / 8 waves (4 row x 2 col), 48 KB LDS -> 3 blocks/CU.
// __launch_bounds__(512, 4): VGPR cap 128 (no spill; R9's (512,6) spilled).
// Used for QKV (18x50) and FF1 (24x50) where the grid stays >=900 blocks.
// ---------------------------------------------------------------------------
template <int EPI, typename OT>
__global__ __launch_bounds__(512, 4) void mgemm256x128_k(const __hip_bfloat16* __restrict__ A,
                                                         const __hip_bfloat16* __restrict__ Wt,
                                                         const float* __restrict__ bias,
                                                         const float* __restrict__ resid,
                                                         OT* __restrict__ C,
                                                         int M, int N, int K) {
    __shared__ __align__(16) char sA[32768];   // 256 rows x 128B
    __shared__ __align__(16) char sB[16384];   // 128 rows x 128B
    const int t = threadIdx.x;            // 0..511
    const int lane = t & 63, w = t >> 6;  // 8 waves
    const int wr = w >> 1, wc = w & 1;    // 4 x 2 -> 64 x 64 per wave
    const int lrow = lane & 15, lgr = lane >> 4;

    const int gx = gridDim.x;
    const int swz = xcd_swz(blockIdx.y * gx + blockIdx.x, gx * gridDim.y);
    const int bm = (swz / gx) * 256, bn = (swz % gx) * 128;

    const __hip_bfloat16* aSrc[4];
    const __hip_bfloat16* bSrc[2];
    #pragma unroll
    for (int i = 0; i < 4; ++i) {
        int q = t + i * 512;              // 0..2047 -> 256 rows x 8 chunks
        int r = q >> 3, c = q & 7;
        int gc = c ^ (r & 7);
        aSrc[i] = A + (size_t)(bm + r) * K + gc * 8;
    }
    #pragma unroll
    for (int i = 0; i < 2; ++i) {
        int q = t + i * 512;              // 0..1023 -> 128 rows x 8 chunks
        int r = q >> 3, c = q & 7;
        int gc = c ^ (r & 7);
        bSrc[i] = Wt + (size_t)(bn + r) * K + gc * 8;
    }

    int aoff[4][2], boff[4][2];
    #pragma unroll
    for (int m = 0; m < 4; ++m) {
        int ra = wr * 64 + m * 16 + lrow;
        int rb = wc * 64 + m * 16 + lrow;
        #pragma unroll
        for (int ks = 0; ks < 2; ++ks) {
            aoff[m][ks] = ra * 128 + (((ks * 4 + lgr) ^ (ra & 7)) << 4);
            boff[m][ks] = rb * 128 + (((ks * 4 + lgr) ^ (rb & 7)) << 4);
        }
    }

    fx4 acc[4][4];
    #pragma unroll
    for (int m = 0; m < 4; ++m)
        #pragma unroll
        for (int n = 0; n < 4; ++n)
            #pragma unroll
            for (int e = 0; e < 4; ++e) acc[m][n][e] = 0.f;

    for (int k0 = 0; k0 < K; k0 += 64) {
        #pragma unroll
        for (int i = 0; i < 4; ++i) GLOAD16(aSrc[i] + k0, sA + (t + i * 512) * 16);
        #pragma unroll
        for (int i = 0; i < 2; ++i) GLOAD16(bSrc[i] + k0, sB + (t + i * 512) * 16);
        __syncthreads();
        #pragma unroll
        for (int ks = 0; ks < 2; ++ks) {
            bfx8 av[4], bv[4];
            #pragma unroll
            for (int m = 0; m < 4; ++m) {
                av[m] = *(const bfx8*)(sA + aoff[m][ks]);
                bv[m] = *(const bfx8*)(sB + boff[m][ks]);
            }
            #pragma unroll
            for (int m = 0; m < 4; ++m)
                #pragma unroll
                for (int n = 0; n < 4; ++n)
                    acc[m][n] = __builtin_amdgcn_mfma_f32_16x16x32_bf16(av[m], bv[n], acc[m][n], 0, 0, 0);
        }
        __syncthreads();
    }

    #pragma unroll
    for (int m = 0; m < 4; ++m) {
        #pragma unroll
        for (int n = 0; n < 4; ++n) {
            const int col = bn + wc * 64 + n * 16 + lrow;
            float bv2 = (EPI >= 1) ? bias[col] : 0.f;
            #pragma unroll
            for (int e = 0; e < 4; ++e) {
                const int row = bm + wr * 64 + m * 16 + lgr * 4 + e;
                if (row < M) {
                    float v = acc[m][n][e] + bv2;
                    if (EPI == 2) v = gelu_f(v);
                    if (EPI == 3) v += resid[(size_t)row * N + col];
                    C[(size_t)row * N + col] = (OT)v;
                }
            }
        }
    }
}

// ---------------------------------------------------------------------------
// MFMA fused attention on fused QKV buffer (row stride 2304).
// K read DIRECTLY from global for QK^T B-frags (per-(b,h) K slice = 25 KB,
// L1-resident; frag pattern = contiguous 16B per lane). LDS = VT + P only
// (58 KB) -> 2 blocks/CU (was 1 at 88 KB): doubled wave occupancy.
// ---------------------------------------------------------------------------
__global__ __launch_bounds__(256) void attn_k(const __hip_bfloat16* __restrict__ QKV,
                                              __hip_bfloat16* __restrict__ O) {
    __shared__ __align__(16) char VTs[64 * 464];   // 29696
    __shared__ __align__(16) char Ps[4][7424];     // 4 x (16 rows x 464B)

    const int h = blockIdx.x;
    const int b = blockIdx.y;
    const int t = threadIdx.x;
    const int lane = t & 63, w = t >> 6;
    const int rho = lane & 15, g = lane >> 4;
    const size_t base = (size_t)b * NTOK * 2304;
    const int qoff = h * 64, koff = 768 + h * 64, voff = 1536 + h * 64;
    const size_t obase = ((size_t)b * NTOK) * 768 + h * 64;

    // ---- stage V transposed: VT[d][tok] (reg-staged; pad tokens zeroed) ----
    #pragma unroll
    for (int i = 0; i < 7; ++i) {
        int q = t + i * 256;
        int tok = q >> 3, c = q & 7;
        bfx8 vv = {0, 0, 0, 0, 0, 0, 0, 0};
        if (tok < NTOK) vv = *(const bfx8*)(QKV + base + (size_t)tok * 2304 + voff + c * 8);
        #pragma unroll
        for (int u = 0; u < 8; ++u)
            *(unsigned short*)(VTs + (c * 8 + u) * 464 + tok * 2) = (unsigned short)vv[u];
    }
    __syncthreads();

    char* Pw = Ps[w];
    // per-lane K row base (row = nt*16 + rho)
    const __hip_bfloat16* kRow = QKV + base + (size_t)rho * 2304 + koff;

    for (int qt = w; qt < 13; qt += 4) {
        const int q0 = qt * 16;
        fx4 s[13];
        #pragma unroll
        for (int nt = 0; nt < 13; ++nt)
            #pragma unroll
            for (int e = 0; e < 4; ++e) s[nt][e] = 0.f;
        #pragma unroll
        for (int ks = 0; ks < 2; ++ks) {
            bfx8 av = *(const bfx8*)(QKV + base + (size_t)(q0 + rho) * 2304 + qoff + ks * 32 + g * 8);
            #pragma unroll
            for (int nt = 0; nt < 13; ++nt) {
                bfx8 bv = *(const bfx8*)(kRow + (size_t)nt * 16 * 2304 + ks * 32 + g * 8);
                s[nt] = __builtin_amdgcn_mfma_f32_16x16x32_bf16(av, bv, s[nt], 0, 0, 0);
            }
        }
        float mx[4] = {-1e30f, -1e30f, -1e30f, -1e30f};
        #pragma unroll
        for (int nt = 0; nt < 13; ++nt) {
            #pragma unroll
            for (int e = 0; e < 4; ++e) {
                float v = s[nt][e] * 0.125f;
                if (nt == 12 && rho >= 5) v = -1e30f;
                s[nt][e] = v;
                mx[e] = fmaxf(mx[e], v);
            }
        }
        #pragma unroll
        for (int off = 1; off < 16; off <<= 1)
            #pragma unroll
            for (int e = 0; e < 4; ++e) mx[e] = fmaxf(mx[e], __shfl_xor(mx[e], off));
        float sm[4] = {0.f, 0.f, 0.f, 0.f};
        #pragma unroll
        for (int nt = 0; nt < 13; ++nt)
            #pragma unroll
            for (int e = 0; e < 4; ++e) {
                float p = __expf(s[nt][e] - mx[e]);
                s[nt][e] = p;
                sm[e] += p;
            }
        #pragma unroll
        for (int off = 1; off < 16; off <<= 1)
            #pragma unroll
            for (int e = 0; e < 4; ++e) sm[e] += __shfl_xor(sm[e], off);
        float inv[4];
        #pragma unroll
        for (int e = 0; e < 4; ++e) inv[e] = 1.0f / sm[e];

        #pragma unroll
        for (int nt = 0; nt < 13; ++nt)
            #pragma unroll
            for (int e = 0; e < 4; ++e) {
                int row = g * 4 + e;
                int col = nt * 16 + rho;
                *(__hip_bfloat16*)(Pw + row * 464 + col * 2) =
                    (__hip_bfloat16)(s[nt][e] * inv[e]);
            }
        #pragma unroll
        for (int e = 0; e < 4; ++e)
            *(__hip_bfloat16*)(Pw + (g * 4 + e) * 464 + (208 + rho) * 2) = (__hip_bfloat16)0.0f;

        __builtin_amdgcn_sched_barrier(0);
        asm volatile("s_waitcnt lgkmcnt(0)" ::: "memory");
        __builtin_amdgcn_sched_barrier(0);

        #pragma unroll
        for (int dt = 0; dt < 4; ++dt) {
            fx4 o;
            #pragma unroll
            for (int e = 0; e < 4; ++e) o[e] = 0.f;
            #pragma unroll
            for (int ks = 0; ks < 7; ++ks) {
                bfx8 pa = *(const bfx8*)(Pw + rho * 464 + (ks * 4 + g) * 16);
                bfx8 bv = *(const bfx8*)(VTs + (dt * 16 + rho) * 464 + (ks * 4 + g) * 16);
                o = __builtin_amdgcn_mfma_f32_16x16x32_bf16(pa, bv, o, 0, 0, 0);
            }
            #pragma unroll
            for (int e = 0; e < 4; ++e) {
                int qrow = q0 + g * 4 + e;
                if (qrow < NTOK)
                    O[obase + (size_t)qrow * 768 + dt * 16 + rho] = (__hip_bfloat16)o[e];
            }
        }
    }
}

// ---------------------------------------------------------------------------
// Head softmax: out[b,:] = softmax(logits[b,:1000] + b_head)
// ---------------------------------------------------------------------------
__global__ __launch_bounds__(256) void shead_k(const float* __restrict__ logits,
                                               const float* __restrict__ bh,
                                               float* __restrict__ out) {
    const int b = blockIdx.x;
    const int t = threadIdx.x;
    __shared__ float lg[1000];
    __shared__ float red[4];

    for (int c = t; c < 1000; c += 256) lg[c] = logits[(size_t)b * 1024 + c] + bh[c];
    __syncthreads();

    float m = -1e30f;
    for (int c = t; c < 1000; c += 256) m = fmaxf(m, lg[c]);
    #pragma unroll
    for (int off = 32; off; off >>= 1) m = fmaxf(m, __shfl_xor(m, off));
    if ((t & 63) == 0) red[t >> 6] = m;
    __syncthreads();
    m = fmaxf(fmaxf(red[0], red[1]), fmaxf(red[2], red[3]));
    __syncthreads();

    float sum = 0.f;
    for (int c = t; c < 1000; c += 256) sum += __expf(lg[c] - m);
    #pragma unroll
    for (int off = 32; off; off >>= 1) sum += __shfl_xor(sum, off);
    if ((t & 63) == 0) red[t >> 6] = sum;
    __syncthreads();
    sum = red[0] + red[1] + red[2] + red[3];
    const float invs = 1.0f / sum;
    for (int c = t; c < 1000; c += 256) out[(size_t)b * 1000 + c] = __expf(lg[c] - m) * invs;
}

// ---------------------------------------------------------------------------
// Driver
// ---------------------------------------------------------------------------
extern "C" void kernel_launch(void* const* d_in, const int* in_sizes, int n_in,
                              void* d_out, int out_size, void* d_ws, size_t ws_size,
                              hipStream_t stream) {
    const float* x        = (const float*)d_in[0];
    const float* ln_p_g   = (const float*)d_in[1];
    const float* ln_p_b   = (const float*)d_in[2];
    const float* W_patch  = (const float*)d_in[3];
    const float* b_patch  = (const float*)d_in[4];
    const float* ln_e_g   = (const float*)d_in[5];
    const float* ln_e_b   = (const float*)d_in[6];
    const float* pos_emb  = (const float*)d_in[7];
    const float* cls_tok  = (const float*)d_in[8];
    const float* ln_a_g   = (const float*)d_in[9];
    const float* ln_a_b   = (const float*)d_in[10];
    const float* Wq       = (const float*)d_in[11];
    const float* Wk       = (const float*)d_in[12];
    const float* Wv       = (const float*)d_in[13];
    const float* Wo       = (const float*)d_in[14];
    const float* bo       = (const float*)d_in[15];
    const float* ln_f_g   = (const float*)d_in[16];
    const float* ln_f_b   = (const float*)d_in[17];
    const float* W1       = (const float*)d_in[18];
    const float* b1       = (const float*)d_in[19];
    const float* W2       = (const float*)d_in[20];
    const float* b2       = (const float*)d_in[21];
    const float* ln_out_g = (const float*)d_in[22];
    const float* ln_out_b = (const float*)d_in[23];
    const float* W_head   = (const float*)d_in[24];
    const float* b_head   = (const float*)d_in[25];

    typedef __hip_bfloat16 bf;
    const int M  = 12608;               // 64*197
    const int MP = 12800;               // padded to 50*256
    char* p = (char*)d_ws;

    float* Z   = (float*)p;            p += (size_t)MP * 768 * 4;      // fp32 residual
    bf* XA     = (bf*)p;               p += (size_t)MP * 768 * 2;      // LN out (bf16)
    bf* QKV    = (bf*)p;               p += (size_t)MP * 2304 * 2;     // fused q,k,v
    bf* OB     = (bf*)p;               p += (size_t)MP * 768 * 2;
    char* FFHc = p;                    p += (size_t)MP * 3072 * 2;     // bf16 GELU buf
    bf* FFH    = (bf*)FFHc;
    float* PE  = (float*)FFHc;                                          // alias: patch-embed fp32
    float* E2  = (float*)(FFHc + (size_t)MP * 768 * 4);                 // alias: ln_e out fp32
    bf* WQKVT  = (bf*)p;               p += (size_t)12 * 2304 * 768 * 2;
    bf* WoT    = (bf*)p;               p += (size_t)12 * 768 * 768 * 2;
    bf* W1T    = (bf*)p;               p += (size_t)12 * 3072 * 768 * 2;
    bf* W2T    = (bf*)p;               p += (size_t)12 * 768 * 3072 * 2;
    bf* WpT    = (bf*)p;               p += (size_t)768 * 768 * 2;
    bf* WhT    = (bf*)p;               p += (size_t)1024 * 768 * 2;
    bf* CLS    = (bf*)p;               p += (size_t)128 * 768 * 2;
    float* LOG = (float*)p;            p += (size_t)64 * 1024 * 4;

    const size_t QKVS = (size_t)2304 * 768;

    // weight convert + transpose (every launch)
    wconv_k<<<dim3(12, 12, 12), 256, 0, stream>>>(Wq, WQKVT,             768, 768,  QKVS);
    wconv_k<<<dim3(12, 12, 12), 256, 0, stream>>>(Wk, WQKVT + 768 * 768, 768, 768,  QKVS);
    wconv_k<<<dim3(12, 12, 12), 256, 0, stream>>>(Wv, WQKVT + 1536 * 768,768, 768,  QKVS);
    wconv_k<<<dim3(12, 12, 12), 256, 0, stream>>>(Wo, WoT,  768, 768,  (size_t)768 * 768);
    wconv_k<<<dim3(48, 12, 12), 256, 0, stream>>>(W1, W1T,  768, 3072, (size_t)3072 * 768);
    wconv_k<<<dim3(12, 48, 12), 256, 0, stream>>>(W2, W2T,  3072, 768, (size_t)768 * 3072);
    wconv_k<<<dim3(12, 12, 1),  256, 0, stream>>>(W_patch, WpT, 768, 768, 0);
    whT_k  <<<dim3(16, 12),     256, 0, stream>>>(W_head, WhT);

    // patch embed pipeline
    patch_ln_k<<<12544, 256, 0, stream>>>(x, XA, ln_p_g, ln_p_b);
    mgemm_k<1, float><<<dim3(6, 98), 256, 0, stream>>>(XA, WpT, b_patch, nullptr, PE, 12544, 768, 768);
    ln_k<float><<<3136, 256, 0, stream>>>(PE, E2, ln_e_g, ln_e_b, 12544);
    build_z_k<<<37824, 256, 0, stream>>>(E2, cls_tok, pos_emb, Z);

    for (int i = 0; i < 12; ++i) {
        bf* WQKVT_i = WQKVT + (size_t)i * QKVS;
        bf* WoT_i   = WoT + (size_t)i * 768 * 768;
        bf* W1T_i   = W1T + (size_t)i * 3072 * 768;
        bf* W2T_i   = W2T + (size_t)i * 768 * 3072;

        ln_k<bf><<<3152, 256, 0, stream>>>(Z, XA, ln_a_g + (size_t)i * 768, ln_a_b + (size_t)i * 768, M);
        mgemm256x128_k<0, bf><<<dim3(18, 50), 512, 0, stream>>>(XA, WQKVT_i, nullptr, nullptr, QKV, M, 2304, 768);
        attn_k<<<dim3(12, 64), 256, 0, stream>>>(QKV, OB);
        mgemm_k<3, float><<<dim3(6, 99), 256, 0, stream>>>(OB, WoT_i, bo + (size_t)i * 768, Z, Z, M, 768, 768);
        ln_k<bf><<<3152, 256, 0, stream>>>(Z, XA, ln_f_g + (size_t)i * 768, ln_f_b + (size_t)i * 768, M);
        mgemm256x128_k<2, bf><<<dim3(24, 50), 512, 0, stream>>>(XA, W1T_i, b1 + (size_t)i * 3072, nullptr, FFH, M, 3072, 768);
        mgemm_k<3, float><<<dim3(6, 99), 256, 0, stream>>>(FFH, W2T_i, b2 + (size_t)i * 768, Z, Z, M, 768, 3072);
    }

    // head: LN(CLS rows) -> logits GEMM (128^2 kernel) -> softmax
    ln_cls_k<<<128, 256, 0, stream>>>(Z, CLS, ln_out_g, ln_out_b);
    mgemm_k<0, float><<<dim3(8, 1), 256, 0, stream>>>(CLS, WhT, nullptr, nullptr, LOG, 64, 1024, 768);
    shead_k<<<64, 256, 0, stream>>>(LOG, b_head, (float*)d_out);
}